// Round 18
// baseline (118.857 us; speedup 1.0000x reference)
//
#include <hip/hip_runtime.h>
#include <math.h>

// Problem constants
constexpr int B  = 4;
constexpr int S  = 2048;
constexpr int DM = 1024;
constexpr int DK = 128;
constexpr int BS = B * S;
constexpr int NSP = 8;      // st-split factor (contention <= 8-way)

static constexpr float SCALE = 0.08838834764831845f; // 1/sqrt(128)

typedef __attribute__((ext_vector_type(8))) short bf16x8;
typedef __attribute__((ext_vector_type(4))) float f32x4;
typedef __attribute__((ext_vector_type(8))) unsigned short u16x8;

__device__ __forceinline__ unsigned short f2bf(float x) {
  unsigned u = __float_as_uint(x);
  unsigned r = (u + 0x7FFFu + ((u >> 16) & 1u)) >> 16;   // RNE
  return (unsigned short)r;
}
__device__ __forceinline__ float bf2f(unsigned short h) {
  return __uint_as_float(((unsigned)h) << 16);
}

__device__ __forceinline__ void gload16(const void* g, void* l) {
  __builtin_amdgcn_global_load_lds(
      (const __attribute__((address_space(1))) void*)g,
      (__attribute__((address_space(3))) void*)l, 16, 0, 0);
}

// ---------------------------------------------------------------------------
// Prep 1: vin fp32 -> Ah (bf16 RNE) + Al (bf16 of residual), row-major [BS][DM]
// ---------------------------------------------------------------------------
__global__ __launch_bounds__(256) void cvt_hilo(
    const float* __restrict__ x, unsigned short* __restrict__ hi,
    unsigned short* __restrict__ lo)
{
  const size_t idx = (size_t)blockIdx.x * 256 + threadIdx.x;  // float4 index
  const float4 v = ((const float4*)x)[idx];
  ushort4 h, l;
  h.x = f2bf(v.x); l.x = f2bf(v.x - bf2f(h.x));
  h.y = f2bf(v.y); l.y = f2bf(v.y - bf2f(h.y));
  h.z = f2bf(v.z); l.z = f2bf(v.z - bf2f(h.z));
  h.w = f2bf(v.w); l.w = f2bf(v.w - bf2f(h.w));
  ((ushort4*)hi)[idx] = h;
  ((ushort4*)lo)[idx] = l;
}

// ---------------------------------------------------------------------------
// Prep 2: w_q/w_k/w_v [1024][128] fp32 -> Wt hi/lo bf16 [384][1024] (B^T)
// ---------------------------------------------------------------------------
__global__ void cvtw_kernel(const float* __restrict__ wq, const float* __restrict__ wk,
                            const float* __restrict__ wv,
                            unsigned short* __restrict__ Wth, unsigned short* __restrict__ Wtl)
{
  const int n = blockIdx.x;            // 0..383
  const int p = n >> 7, c = n & 127;
  const float* w = (p == 0) ? wq : (p == 1) ? wk : wv;
  for (int k = threadIdx.x; k < DM; k += 256) {
    const float x = w[(size_t)k * DK + c];
    const unsigned short h = f2bf(x);
    Wth[(size_t)n * DM + k] = h;
    Wtl[(size_t)n * DM + k] = f2bf(x - bf2f(h));
  }
}

// ---------------------------------------------------------------------------
// Kernel A: projections via split-bf16 MFMA. Tile 128x64 (M x N), BK=64,
// grid (BS/128, 6) = 384 blocks, LDS 48 KB -> 3 blocks/CU. Each wave owns a
// 64x32 sub-tile (acc[4][2]): 48 MFMA per k-step vs 6 gload16/thread — 2x
// the compute density of the old 64x64 tile. k-chain per output element
// unchanged -> outputs bitwise identical to the previous proj.
// ---------------------------------------------------------------------------
__global__ __launch_bounds__(256) void proj_mfma(
    const unsigned short* __restrict__ Ah, const unsigned short* __restrict__ Al,
    const unsigned short* __restrict__ Wh, const unsigned short* __restrict__ Wl,
    unsigned short* __restrict__ qh, unsigned short* __restrict__ ql,
    unsigned short* __restrict__ kh, unsigned short* __restrict__ kl,
    float* __restrict__ vtmp)
{
  __shared__ unsigned short Ash[2][128 * 64];   // A hi/lo (32 KB)
  __shared__ unsigned short Wsh[2][64 * 64];    // W hi/lo (16 KB)

  const int r0 = blockIdx.x * 128;     // M tile (8192/128 = 64)
  const int n0 = blockIdx.y * 64;      // N tile (384/64 = 6)
  const int t  = threadIdx.x;
  const int l  = t & 63, w = t >> 6;
  const int wm = w >> 1, wn = w & 1;   // 2x2 wave grid: rows wm*64, cols wn*32
  const int fr = l & 15, kg = l >> 4;  // fragment row / k-group

  f32x4 acc[4][2] = {};

  for (int k0 = 0; k0 < DM; k0 += 64) {
    // stage A 128x64 hi/lo (1024 16B segs per buffer)
    #pragma unroll
    for (int i = 0; i < 4; ++i) {
      const int flat = t + i * 256;
      const int row = flat >> 3, sg = flat & 7;
      const int sgs = sg ^ (row & 7);        // pre-swizzled source (T2)
      const size_t ga = (size_t)(r0 + row) * DM + k0 + sgs * 8;
      gload16(Ah + ga, &Ash[0][flat * 8]);
      gload16(Al + ga, &Ash[1][flat * 8]);
    }
    // stage W 64x64 hi/lo (512 segs per buffer)
    #pragma unroll
    for (int i = 0; i < 2; ++i) {
      const int flat = t + i * 256;
      const int row = flat >> 3, sg = flat & 7;
      const int sgs = sg ^ (row & 7);
      const size_t gw = (size_t)(n0 + row) * DM + k0 + sgs * 8;
      gload16(Wh + gw, &Wsh[0][flat * 8]);
      gload16(Wl + gw, &Wsh[1][flat * 8]);
    }
    __syncthreads();

    __builtin_amdgcn_s_setprio(1);
    #pragma unroll
    for (int kk = 0; kk < 2; ++kk) {
      bf16x8 ah[4], al[4], bh[2], bl[2];
      #pragma unroll
      for (int im = 0; im < 4; ++im) {
        const int row = wm * 64 + im * 16 + fr;
        const int off = row * 64 + ((kk * 4 + kg) ^ (row & 7)) * 8;
        ah[im] = *(const bf16x8*)&Ash[0][off];
        al[im] = *(const bf16x8*)&Ash[1][off];
      }
      #pragma unroll
      for (int in = 0; in < 2; ++in) {
        const int row = wn * 32 + in * 16 + fr;
        const int off = row * 64 + ((kk * 4 + kg) ^ (row & 7)) * 8;
        bh[in] = *(const bf16x8*)&Wsh[0][off];
        bl[in] = *(const bf16x8*)&Wsh[1][off];
      }
      #pragma unroll
      for (int im = 0; im < 4; ++im)
        #pragma unroll
        for (int in = 0; in < 2; ++in) {
          acc[im][in] = __builtin_amdgcn_mfma_f32_16x16x32_bf16(ah[im], bh[in], acc[im][in], 0, 0, 0);
          acc[im][in] = __builtin_amdgcn_mfma_f32_16x16x32_bf16(ah[im], bl[in], acc[im][in], 0, 0, 0);
          acc[im][in] = __builtin_amdgcn_mfma_f32_16x16x32_bf16(al[im], bh[in], acc[im][in], 0, 0, 0);
        }
    }
    __builtin_amdgcn_s_setprio(0);
    __syncthreads();
  }

  // Epilogue: C/D layout col = lane&15, row = (lane>>4)*4 + reg
  const int crow = kg * 4;
  #pragma unroll
  for (int im = 0; im < 4; ++im)
    #pragma unroll
    for (int in = 0; in < 2; ++in) {
      const int n = n0 + wn * 32 + in * 16 + fr;
      const int p = n >> 7, c = n & 127;           // p uniform per block
      #pragma unroll
      for (int r = 0; r < 4; ++r) {
        const int m = r0 + wm * 64 + im * 16 + crow + r;
        const float val = acc[im][in][r];
        if (p == 2) {
          vtmp[(size_t)m * DK + c] = val;
        } else {
          const unsigned short h = f2bf(val);
          const unsigned short lo2 = f2bf(val - bf2f(h));
          unsigned short* hd = p ? kh : qh;
          unsigned short* ld = p ? kl : ql;
          hd[(size_t)m * DK + c] = h;
          ld[(size_t)m * DK + c] = lo2;
        }
      }
    }
}

// ---------------------------------------------------------------------------
// Prep 3: transpose v fp32 [B][S][128] -> vT hi/lo bf16 [B][128][S]
// ---------------------------------------------------------------------------
__global__ __launch_bounds__(256) void cvtv_kernel(
    const float* __restrict__ v, unsigned short* __restrict__ vTh,
    unsigned short* __restrict__ vTl)
{
  const int s0 = blockIdx.x * 64, d0 = blockIdx.y * 64, b = blockIdx.z;
  __shared__ float Ts[64][65];
  const int t = threadIdx.x;
  const int r = t >> 4, c4 = (t & 15) * 4;
  #pragma unroll
  for (int rr = 0; rr < 4; ++rr) {
    const int sl = r + 16 * rr;
    *(float4*)&Ts[sl][c4] =
        *(const float4*)&v[((size_t)b * S + s0 + sl) * DK + d0 + c4];
  }
  __syncthreads();
  const int dl = t >> 2, sq = (t & 3) * 16;
  unsigned short hbuf[16], lbuf[16];
  #pragma unroll
  for (int j = 0; j < 16; ++j) {
    const float val = Ts[sq + j][dl];
    hbuf[j] = f2bf(val);
    lbuf[j] = f2bf(val - bf2f(hbuf[j]));
  }
  const size_t o = (size_t)b * DK * S + (size_t)(d0 + dl) * S + s0 + sq;
  #pragma unroll
  for (int half = 0; half < 2; ++half) {
    *(u16x8*)&vTh[o + half * 8] = *(u16x8*)&hbuf[half * 8];
    *(u16x8*)&vTl[o + half * 8] = *(u16x8*)&lbuf[half * 8];
  }
}

// ---------------------------------------------------------------------------
// Kernel B: column-softmax STATS ONLY. grid (NSP, 32, B); block (sp, qt)
// loops st = sp, sp+NSP, ... <= qt. Q staged once; K for tile st+NSP is
// issued right after tile st's score MFMAs (Ksh dead then) so its latency
// hides under the stats VALU reduce. 2 barriers/tile.
// ---------------------------------------------------------------------------
__global__ __launch_bounds__(256) void stats_mfma(
    const unsigned short* __restrict__ qh, const unsigned short* __restrict__ ql,
    const unsigned short* __restrict__ kh, const unsigned short* __restrict__ kl,
    float* __restrict__ pm, float* __restrict__ ps)
{
  const int sp = blockIdx.x, qt = blockIdx.y, b = blockIdx.z;
  if (sp > qt) return;
  const int q0 = qt * 64;

  __shared__ unsigned short Bsh[64 * 128], Bsl[64 * 128];   // Q stage / K
  __shared__ float SmL[64 * 2], SeL[64 * 2];

  const int t = threadIdx.x;
  const int l = t & 63, w = t >> 6;
  const int wm = w >> 1, wn = w & 1;
  const int fr = l & 15, kg = l >> 4;

  auto stage_K = [&](int s0k) {
    #pragma unroll
    for (int i = 0; i < 4; ++i) {
      const int flat = t + i * 256;
      const int row = flat >> 4, sg = flat & 15;
      const int sgs = sg ^ (row & 7);
      const size_t gk = (size_t)(b * S + s0k + row) * DK + sgs * 8;
      gload16(kh + gk, &Bsh[flat * 8]);
      gload16(kl + gk, &Bsl[flat * 8]);
    }
  };

  // ---- stage Q once, pull fragments to registers ----
  #pragma unroll
  for (int i = 0; i < 4; ++i) {
    const int flat = t + i * 256;
    const int row = flat >> 4, sg = flat & 15;
    const int sgs = sg ^ (row & 7);
    const size_t gq = (size_t)(b * S + q0 + row) * DK + sgs * 8;
    gload16(qh + gq, &Bsh[flat * 8]);
    gload16(ql + gq, &Bsl[flat * 8]);
  }
  __syncthreads();
  bf16x8 qfh[2][4], qfl[2][4];
  #pragma unroll
  for (int im = 0; im < 2; ++im)
    #pragma unroll
    for (int ks = 0; ks < 4; ++ks) {
      const int row = wm * 32 + im * 16 + fr;
      const int off = row * 128 + ((ks * 4 + kg) ^ (row & 7)) * 8;
      qfh[im][ks] = *(const bf16x8*)&Bsh[off];
      qfl[im][ks] = *(const bf16x8*)&Bsl[off];
    }
  __syncthreads();   // Q reads done before K overwrites

  stage_K(sp * 64);  // prologue: first K tile

  for (int st = sp; st <= qt; st += NSP) {
    const int s0 = st * 64;
    __syncthreads();   // drains K(st); orders prev SmL/SeL reuse

    // ---- scores (order must match fused_pv exactly) ----
    f32x4 sacc[2][2] = {};
    __builtin_amdgcn_s_setprio(1);
    #pragma unroll
    for (int ks = 0; ks < 4; ++ks) {
      bf16x8 bh[2], bl[2];
      #pragma unroll
      for (int in = 0; in < 2; ++in) {
        const int row = wn * 32 + in * 16 + fr;
        const int off = row * 128 + ((ks * 4 + kg) ^ (row & 7)) * 8;
        bh[in] = *(const bf16x8*)&Bsh[off];
        bl[in] = *(const bf16x8*)&Bsl[off];
      }
      #pragma unroll
      for (int im = 0; im < 2; ++im)
        #pragma unroll
        for (int in = 0; in < 2; ++in) {
          sacc[im][in] = __builtin_amdgcn_mfma_f32_16x16x32_bf16(qfh[im][ks], bh[in], sacc[im][in], 0, 0, 0);
          sacc[im][in] = __builtin_amdgcn_mfma_f32_16x16x32_bf16(qfh[im][ks], bl[in], sacc[im][in], 0, 0, 0);
          sacc[im][in] = __builtin_amdgcn_mfma_f32_16x16x32_bf16(qfl[im][ks], bh[in], sacc[im][in], 0, 0, 0);
        }
    }
    __builtin_amdgcn_s_setprio(0);

    // ---- prefetch next K tile (Ksh dead now; hides under stats VALU) ----
    if (st + NSP <= qt) stage_K((st + NSP) * 64);

    // ---- column stats (softmax over q within this 64-row chunk) ----
    const bool diag = (st == qt);
    float Sm_[2], Se_[2];
    #pragma unroll
    for (int in = 0; in < 2; ++in) {
      const int scol = s0 + wn * 32 + in * 16 + fr;
      float m8 = -INFINITY;
      #pragma unroll
      for (int im = 0; im < 2; ++im)
        #pragma unroll
        for (int r = 0; r < 4; ++r) {
          const int q = q0 + wm * 32 + im * 16 + kg * 4 + r;
          if (!diag || q >= scol) m8 = fmaxf(m8, sacc[im][in][r] * SCALE);
        }
      float e8 = 0.f;
      if (m8 > -INFINITY) {
        #pragma unroll
        for (int im = 0; im < 2; ++im)
          #pragma unroll
          for (int r = 0; r < 4; ++r) {
            const int q = q0 + wm * 32 + im * 16 + kg * 4 + r;
            if (!diag || q >= scol) e8 += __expf(sacc[im][in][r] * SCALE - m8);
          }
      }
      #pragma unroll
      for (int off = 16; off <= 32; off <<= 1) {
        const float om = __shfl_xor(m8, off);
        const float oe = __shfl_xor(e8, off);
        const float nm = fmaxf(m8, om);
        float ne = 0.f;
        if (m8 > -INFINITY) ne += e8 * __expf(m8 - nm);
        if (om > -INFINITY) ne += oe * __expf(om - nm);
        m8 = nm; e8 = ne;
      }
      Sm_[in] = m8; Se_[in] = e8;
    }
    if (l < 16) {
      #pragma unroll
      for (int in = 0; in < 2; ++in) {
        const int col = wn * 32 + in * 16 + l;
        SmL[col * 2 + wm] = Sm_[in];
        SeL[col * 2 + wm] = Se_[in];
      }
    }
    __syncthreads();
    if (t < 64) {
      const float m0 = SmL[t * 2 + 0], m1 = SmL[t * 2 + 1];
      const float nm = fmaxf(m0, m1);
      float ne = 0.f;
      if (m0 > -INFINITY) ne += SeL[t * 2 + 0] * __expf(m0 - nm);
      if (m1 > -INFINITY) ne += SeL[t * 2 + 1] * __expf(m1 - nm);
      const size_t o = ((size_t)(b * 32 + qt)) * S + s0 + t;
      pm[o] = nm;
      ps[o] = ne;
    }
    // loop-top barrier orders SmL reuse + drains prefetched K
  }
}

// ---------------------------------------------------------------------------
// Kernel C: combine 32 row-chunk partials -> per-column max m and 1/sum.
// ---------------------------------------------------------------------------
__global__ void colcombine_kernel(const float* __restrict__ pm, const float* __restrict__ ps,
                                  float* __restrict__ cm, float* __restrict__ cinv)
{
  const int s = blockIdx.x * 256 + threadIdx.x;
  const int b = blockIdx.y;
  const int ch0 = s >> 6;
  float m = -INFINITY;
  for (int ch = ch0; ch < 32; ++ch)
    m = fmaxf(m, pm[((size_t)(b * 32 + ch)) * S + s]);
  float sum = 0.f;
  for (int ch = ch0; ch < 32; ++ch) {
    const size_t i = ((size_t)(b * 32 + ch)) * S + s;
    sum += ps[i] * __expf(pm[i] - m);
  }
  cm[(size_t)b * S + s]   = m;
  cinv[(size_t)b * S + s] = 1.f / sum;   // sum >= 1 (diagonal element)
}

// ---------------------------------------------------------------------------
// zero out (out is atomically accumulated)
// ---------------------------------------------------------------------------
__global__ void zero_out_kernel(float* __restrict__ out)
{
  const size_t idx = (size_t)blockIdx.x * 256 + threadIdx.x;
  ((float4*)out)[idx] = float4{0.f, 0.f, 0.f, 0.f};
}

// ---------------------------------------------------------------------------
// Kernel D: fused second pass. grid (NSP, 32, B); block (sp, qt) loops
// st = sp, sp+NSP, ... <= qt, accumulating PV in registers; one atomic
// epilogue per block. Pipeline: V(st) issued at top with prev tile's
// deferred att/mirror stores in its shadow; K(st+NSP) issued after the
// P-visible barrier so its latency hides under PV.
// Scores recomputed bitwise-identical to stats_mfma. LDS 72 KB.
// ---------------------------------------------------------------------------
__global__ __launch_bounds__(256) void fused_pv(
    const unsigned short* __restrict__ qh, const unsigned short* __restrict__ ql,
    const unsigned short* __restrict__ kh, const unsigned short* __restrict__ kl,
    const unsigned short* __restrict__ vTh, const unsigned short* __restrict__ vTl,
    const float* __restrict__ cm, const float* __restrict__ cinv,
    float* __restrict__ att, float* __restrict__ out)
{
  const int sp = blockIdx.x, qt = blockIdx.y, b = blockIdx.z;
  if (sp > qt) return;
  const int q0 = qt * 64;
  float* attb = att + (size_t)b * S * S;
  const unsigned short* vth = vTh + (size_t)b * DK * S;
  const unsigned short* vtl = vTl + (size_t)b * DK * S;

  __shared__ unsigned short Ksh[64 * 128], Ksl[64 * 128];   // Q stage / K (32 KB)
  __shared__ unsigned short Vsh[128 * 64], Vsl[128 * 64];   // vT tile (32 KB)
  __shared__ unsigned short Psh[64 * 64];                   // P tile (8 KB)

  const int t = threadIdx.x;
  const int l = t & 63, w = t >> 6;
  const int wm = w >> 1, wn = w & 1;          // 2x2 wave grid (scores)
  const int fr = l & 15, kg = l >> 4;

  auto stage_K = [&](int s0k) {
    #pragma unroll
    for (int i = 0; i < 4; ++i) {
      const int flat = t + i * 256;
      const int row = flat >> 4, sg = flat & 15;
      const int sgs = sg ^ (row & 7);
      const size_t gk = (size_t)(b * S + s0k + row) * DK + sgs * 8;
      gload16(kh + gk, &Ksh[flat * 8]);
      gload16(kl + gk, &Ksl[flat * 8]);
    }
  };

  // ---- stage Q tile once, pull fragments to registers ----
  #pragma unroll
  for (int i = 0; i < 4; ++i) {
    const int flat = t + i * 256;
    const int row = flat >> 4, sg = flat & 15;
    const int sgs = sg ^ (row & 7);
    const size_t gq = (size_t)(b * S + q0 + row) * DK + sgs * 8;
    gload16(qh + gq, &Ksh[flat * 8]);
    gload16(ql + gq, &Ksl[flat * 8]);
  }
  __syncthreads();
  bf16x8 qfh[2][4], qfl[2][4];
  #pragma unroll
  for (int im = 0; im < 2; ++im)
    #pragma unroll
    for (int ks = 0; ks < 4; ++ks) {
      const int row = wm * 32 + im * 16 + fr;
      const int off = row * 128 + ((ks * 4 + kg) ^ (row & 7)) * 8;
      qfh[im][ks] = *(const bf16x8*)&Ksh[off];
      qfl[im][ks] = *(const bf16x8*)&Ksl[off];
    }
  __syncthreads();   // all Q reads done before K overwrites

  stage_K(sp * 64);  // prologue: first K tile

  f32x4 acc[8] = {};     // PV accumulator, persists across st tiles
  float xv[2][2][4];     // previous tile's normalized att values
  int prev_s0 = -1;
  int prev_mirror = 0;

  for (int st = sp; st <= qt; st += NSP) {
    const int s0 = st * 64;

    // ---- stage V tile (issue) ----
    #pragma unroll
    for (int i = 0; i < 4; ++i) {
      const int flat = t + i * 256;
      const int row = flat >> 3, sg = flat & 7;
      const int sgs = sg ^ (row & 7);
      const size_t gv = (size_t)row * S + s0 + sgs * 8;
      gload16(vth + gv, &Vsh[flat * 8]);
      gload16(vtl + gv, &Vsl[flat * 8]);
    }

    // ---- deferred att/mirror stores for the PREVIOUS tile (load shadow) ----
    if (prev_s0 >= 0) {
      if (prev_mirror) {
        const f32x4 z = {0.f, 0.f, 0.f, 0.f};
        #pragma unroll
        for (int i = 0; i < 4; ++i) {
          const int flat = t + i * 256;
          const int row = flat >> 4, c4 = (flat & 15) * 4;
          __builtin_nontemporal_store(z, (f32x4*)&attb[(size_t)(prev_s0 + row) * S + q0 + c4]);
        }
      }
      #pragma unroll
      for (int im = 0; im < 2; ++im)
        #pragma unroll
        for (int in = 0; in < 2; ++in) {
          const int sloc = wn * 32 + in * 16 + fr;
          #pragma unroll
          for (int r = 0; r < 4; ++r) {
            const int qloc = wm * 32 + im * 16 + kg * 4 + r;
            __builtin_nontemporal_store(xv[im][in][r],
                                        &attb[(size_t)(q0 + qloc) * S + prev_s0 + sloc]);
          }
        }
    }
    __syncthreads();   // joint drain: K(st) [prefetched] + V loads + stores

    // ---- scores: identical accumulation order to stats_mfma ----
    f32x4 sacc[2][2] = {};
    __builtin_amdgcn_s_setprio(1);
    #pragma unroll
    for (int ks = 0; ks < 4; ++ks) {
      bf16x8 bh[2], bl[2];
      #pragma unroll
      for (int in = 0; in < 2; ++in) {
        const int row = wn * 32 + in * 16 + fr;
        const int off = row * 128 + ((ks * 4 + kg) ^ (row & 7)) * 8;
        bh[in] = *(const bf16x8*)&Ksh[off];
        bl[in] = *(const bf16x8*)&Ksl[off];
      }
      #pragma unroll
      for (int im = 0; im < 2; ++im)
        #pragma unroll
        for (int in = 0; in < 2; ++in) {
          sacc[im][in] = __builtin_amdgcn_mfma_f32_16x16x32_bf16(qfh[im][ks], bh[in], sacc[im][in], 0, 0, 0);
          sacc[im][in] = __builtin_amdgcn_mfma_f32_16x16x32_bf16(qfh[im][ks], bl[in], sacc[im][in], 0, 0, 0);
          sacc[im][in] = __builtin_amdgcn_mfma_f32_16x16x32_bf16(qfl[im][ks], bh[in], sacc[im][in], 0, 0, 0);
        }
    }
    __builtin_amdgcn_s_setprio(0);

    // ---- normalize in-register; P (plain bf16) -> LDS; keep xv in regs ----
    const bool diag = (st == qt);
    #pragma unroll
    for (int in = 0; in < 2; ++in) {
      const int sloc = wn * 32 + in * 16 + fr;
      const int scol = s0 + sloc;
      const float m   = cm[(size_t)b * S + scol];
      const float inv = cinv[(size_t)b * S + scol];
      #pragma unroll
      for (int im = 0; im < 2; ++im) {
        #pragma unroll
        for (int r = 0; r < 4; ++r) {
          const int qloc = wm * 32 + im * 16 + kg * 4 + r;
          const bool live = !diag || (q0 + qloc >= scol);
          const float x = live ? __expf(sacc[im][in][r] * SCALE - m) * inv : 0.f;
          xv[im][in][r] = x;
          const int idx = qloc * 64 + (((sloc >> 3) ^ (qloc & 7)) * 8 + (sloc & 7));
          Psh[idx] = f2bf(x);
        }
      }
    }
    __syncthreads();   // P visible; Ksh now dead

    // ---- prefetch next K tile into Ksh (hides under PV) ----
    if (st + NSP <= qt) stage_K((st + NSP) * 64);

    // ---- PV: wave w computes q rows [w*16, w*16+16), all 128 d cols ----
    __builtin_amdgcn_s_setprio(1);
    #pragma unroll
    for (int ks2 = 0; ks2 < 2; ++ks2) {
      const int arow = w * 16 + fr;
      const int aoff = arow * 64 + ((ks2 * 4 + kg) ^ (arow & 7)) * 8;
      const bf16x8 a = *(const bf16x8*)&Psh[aoff];
      #pragma unroll
      for (int in = 0; in < 8; ++in) {
        const int brow = in * 16 + fr;
        const int boff = brow * 64 + ((ks2 * 4 + kg) ^ (brow & 7)) * 8;
        const bf16x8 b_h = *(const bf16x8*)&Vsh[boff];
        const bf16x8 b_l = *(const bf16x8*)&Vsl[boff];
        acc[in] = __builtin_amdgcn_mfma_f32_16x16x32_bf16(a, b_h, acc[in], 0, 0, 0);
        acc[in] = __builtin_amdgcn_mfma_f32_16x16x32_bf16(a, b_l, acc[in], 0, 0, 0);
      }
    }
    __builtin_amdgcn_s_setprio(0);
    __syncthreads();   // Vsh/Psh reads done before next-iter V staging

    prev_s0 = s0;
    prev_mirror = (st < qt) ? 1 : 0;
  }

  // ---- final tile's deferred stores ----
  if (prev_s0 >= 0) {
    if (prev_mirror) {
      const f32x4 z = {0.f, 0.f, 0.f, 0.f};
      #pragma unroll
      for (int i = 0; i < 4; ++i) {
        const int flat = t + i * 256;
        const int row = flat >> 4, c4 = (flat & 15) * 4;
        __builtin_nontemporal_store(z, (f32x4*)&attb[(size_t)(prev_s0 + row) * S + q0 + c4]);
      }
    }
    #pragma unroll
    for (int im = 0; im < 2; ++im)
      #pragma unroll
      for (int in = 0; in < 2; ++in) {
        const int sloc = wn * 32 + in * 16 + fr;
        #pragma unroll
        for (int r = 0; r < 4; ++r) {
          const int qloc = wm * 32 + im * 16 + kg * 4 + r;
          __builtin_nontemporal_store(xv[im][in][r],
                                      &attb[(size_t)(q0 + qloc) * S + prev_s0 + sloc]);
        }
      }
  }

  // ---- single atomic epilogue per block ----
  #pragma unroll
  for (int in = 0; in < 8; ++in) {
    #pragma unroll
    for (int r = 0; r < 4; ++r) {
      const int q = q0 + w * 16 + kg * 4 + r;
      const int d = in * 16 + fr;
      atomicAdd(&out[((size_t)b * S + q) * DK + d], acc[in][r]);
    }
  }
}

// ---------------------------------------------------------------------------
extern "C" void kernel_launch(void* const* d_in, const int* in_sizes, int n_in,
                              void* d_out, int out_size, void* d_ws, size_t ws_size,
                              hipStream_t stream)
{
  const float* vin = (const float*)d_in[0];
  const float* wq  = (const float*)d_in[1];
  const float* wk  = (const float*)d_in[2];
  const float* wv  = (const float*)d_in[3];

  float* out = (float*)d_out;
  float* att = out + (size_t)B * S * DK;     // attention output region (64 MB)

  // bf16 copies of vin / W live INSIDE the att region (dead before att writes)
  unsigned short* Ah  = (unsigned short*)att;
  unsigned short* Al  = Ah  + (size_t)BS * DM;
  unsigned short* Wth = Al  + (size_t)BS * DM;
  unsigned short* Wtl = Wth + (size_t)384 * DM;

  constexpr size_t NE = (size_t)BS * DK;     // 1048576
  unsigned short* qh  = (unsigned short*)d_ws;
  unsigned short* ql  = qh  + NE;
  unsigned short* kh  = ql  + NE;
  unsigned short* kl  = kh  + NE;
  unsigned short* vTh = kl  + NE;
  unsigned short* vTl = vTh + NE;
  float* vtmp = (float*)(vTl + NE);          // 4 MB
  float* pm   = vtmp;                        // aliases vtmp (v dead by then)
  float* ps   = pm + 32ull * B * S;          // 1 MB each
  float* cm   = ps + 32ull * B * S;
  float* cinv = cm + (size_t)B * S;

  cvt_hilo         <<<dim3(BS * DM / 1024),  256, 0, stream>>>(vin, Ah, Al);
  cvtw_kernel      <<<dim3(384),             256, 0, stream>>>(wq, wk, wv, Wth, Wtl);
  proj_mfma        <<<dim3(BS / 128, 6),     256, 0, stream>>>(Ah, Al, Wth, Wtl,
                                                               qh, ql, kh, kl, vtmp);
  cvtv_kernel      <<<dim3(S / 64, 2, B),    256, 0, stream>>>(vtmp, vTh, vTl);
  zero_out_kernel  <<<dim3(BS * DK / 1024),  256, 0, stream>>>(out);
  stats_mfma       <<<dim3(NSP, 32, B),      256, 0, stream>>>(qh, ql, kh, kl, pm, ps);
  colcombine_kernel<<<dim3(S / 256, B),      256, 0, stream>>>(pm, ps, cm, cinv);
  fused_pv         <<<dim3(NSP, 32, B),      256, 0, stream>>>(qh, ql, kh, kl, vTh, vTl,
                                                               cm, cinv, att, out);
}

// Round 19
// 114.967 us; speedup vs baseline: 1.0338x; 1.0338x over previous
//
#include <hip/hip_runtime.h>
#include <math.h>

// Problem constants
constexpr int B  = 4;
constexpr int S  = 2048;
constexpr int DM = 1024;
constexpr int DK = 128;
constexpr int BS = B * S;
constexpr int NSP    = 8;   // st-split factor for stats (4 blocks/CU fits 912)
constexpr int NSP_PV = 4;   // st-split for fused_pv: 488 blocks = ONE resident
                            // generation at 2 blocks/CU (72 KB LDS)

static constexpr float SCALE = 0.08838834764831845f; // 1/sqrt(128)

typedef __attribute__((ext_vector_type(8))) short bf16x8;
typedef __attribute__((ext_vector_type(4))) float f32x4;
typedef __attribute__((ext_vector_type(8))) unsigned short u16x8;

__device__ __forceinline__ unsigned short f2bf(float x) {
  unsigned u = __float_as_uint(x);
  unsigned r = (u + 0x7FFFu + ((u >> 16) & 1u)) >> 16;   // RNE
  return (unsigned short)r;
}
__device__ __forceinline__ float bf2f(unsigned short h) {
  return __uint_as_float(((unsigned)h) << 16);
}

__device__ __forceinline__ void gload16(const void* g, void* l) {
  __builtin_amdgcn_global_load_lds(
      (const __attribute__((address_space(1))) void*)g,
      (__attribute__((address_space(3))) void*)l, 16, 0, 0);
}

// ---------------------------------------------------------------------------
// Prep 1: vin fp32 -> Ah (bf16 RNE) + Al (bf16 of residual), row-major [BS][DM]
// ---------------------------------------------------------------------------
__global__ __launch_bounds__(256) void cvt_hilo(
    const float* __restrict__ x, unsigned short* __restrict__ hi,
    unsigned short* __restrict__ lo)
{
  const size_t idx = (size_t)blockIdx.x * 256 + threadIdx.x;  // float4 index
  const float4 v = ((const float4*)x)[idx];
  ushort4 h, l;
  h.x = f2bf(v.x); l.x = f2bf(v.x - bf2f(h.x));
  h.y = f2bf(v.y); l.y = f2bf(v.y - bf2f(h.y));
  h.z = f2bf(v.z); l.z = f2bf(v.z - bf2f(h.z));
  h.w = f2bf(v.w); l.w = f2bf(v.w - bf2f(h.w));
  ((ushort4*)hi)[idx] = h;
  ((ushort4*)lo)[idx] = l;
}

// ---------------------------------------------------------------------------
// Prep 2: w_q/w_k/w_v [1024][128] fp32 -> Wt hi/lo bf16 [384][1024] (B^T)
// ---------------------------------------------------------------------------
__global__ void cvtw_kernel(const float* __restrict__ wq, const float* __restrict__ wk,
                            const float* __restrict__ wv,
                            unsigned short* __restrict__ Wth, unsigned short* __restrict__ Wtl)
{
  const int n = blockIdx.x;            // 0..383
  const int p = n >> 7, c = n & 127;
  const float* w = (p == 0) ? wq : (p == 1) ? wk : wv;
  for (int k = threadIdx.x; k < DM; k += 256) {
    const float x = w[(size_t)k * DK + c];
    const unsigned short h = f2bf(x);
    Wth[(size_t)n * DM + k] = h;
    Wtl[(size_t)n * DM + k] = f2bf(x - bf2f(h));
  }
}

// ---------------------------------------------------------------------------
// Kernel A: projections via split-bf16 MFMA (round-17 64x64 tile — the
// 128x64 variant regressed). Emits q,k as bf16 hi/lo pairs and v fp32.
// ---------------------------------------------------------------------------
__global__ __launch_bounds__(256) void proj_mfma(
    const unsigned short* __restrict__ Ah, const unsigned short* __restrict__ Al,
    const unsigned short* __restrict__ Wh, const unsigned short* __restrict__ Wl,
    unsigned short* __restrict__ qh, unsigned short* __restrict__ ql,
    unsigned short* __restrict__ kh, unsigned short* __restrict__ kl,
    float* __restrict__ vtmp)
{
  __shared__ unsigned short Ash[2][64 * 64];
  __shared__ unsigned short Wsh[2][64 * 64];

  const int r0 = blockIdx.x * 64;      // M tile
  const int n0 = blockIdx.y * 64;      // N tile (384/64 = 6)
  const int t  = threadIdx.x;
  const int l  = t & 63, w = t >> 6;
  const int wm = w >> 1, wn = w & 1;   // 2x2 wave grid
  const int fr = l & 15, kg = l >> 4;  // fragment row / k-group

  f32x4 acc[2][2] = {};

  for (int k0 = 0; k0 < DM; k0 += 64) {
    #pragma unroll
    for (int i = 0; i < 2; ++i) {
      const int flat = t + i * 256;          // 512 16B segments per tile
      const int row = flat >> 3, sg = flat & 7;
      const int sgs = sg ^ (row & 7);        // pre-swizzled source (T2)
      const size_t ga = (size_t)(r0 + row) * DM + k0 + sgs * 8;
      const size_t gw = (size_t)(n0 + row) * DM + k0 + sgs * 8;
      gload16(Ah + ga, &Ash[0][flat * 8]);
      gload16(Al + ga, &Ash[1][flat * 8]);
      gload16(Wh + gw, &Wsh[0][flat * 8]);
      gload16(Wl + gw, &Wsh[1][flat * 8]);
    }
    __syncthreads();

    __builtin_amdgcn_s_setprio(1);
    #pragma unroll
    for (int kk = 0; kk < 2; ++kk) {
      bf16x8 ah[2], al[2], bh[2], bl[2];
      #pragma unroll
      for (int im = 0; im < 2; ++im) {
        const int row = wm * 32 + im * 16 + fr;
        const int off = row * 64 + ((kk * 4 + kg) ^ (row & 7)) * 8;
        ah[im] = *(const bf16x8*)&Ash[0][off];
        al[im] = *(const bf16x8*)&Ash[1][off];
      }
      #pragma unroll
      for (int in = 0; in < 2; ++in) {
        const int row = wn * 32 + in * 16 + fr;
        const int off = row * 64 + ((kk * 4 + kg) ^ (row & 7)) * 8;
        bh[in] = *(const bf16x8*)&Wsh[0][off];
        bl[in] = *(const bf16x8*)&Wsh[1][off];
      }
      #pragma unroll
      for (int im = 0; im < 2; ++im)
        #pragma unroll
        for (int in = 0; in < 2; ++in) {
          acc[im][in] = __builtin_amdgcn_mfma_f32_16x16x32_bf16(ah[im], bh[in], acc[im][in], 0, 0, 0);
          acc[im][in] = __builtin_amdgcn_mfma_f32_16x16x32_bf16(ah[im], bl[in], acc[im][in], 0, 0, 0);
          acc[im][in] = __builtin_amdgcn_mfma_f32_16x16x32_bf16(al[im], bh[in], acc[im][in], 0, 0, 0);
        }
    }
    __builtin_amdgcn_s_setprio(0);
    __syncthreads();
  }

  // Epilogue: C/D layout col = lane&15, row = (lane>>4)*4 + reg
  const int crow = kg * 4;
  #pragma unroll
  for (int im = 0; im < 2; ++im)
    #pragma unroll
    for (int in = 0; in < 2; ++in) {
      const int n = n0 + wn * 32 + in * 16 + fr;
      const int p = n >> 7, c = n & 127;           // p uniform per block
      #pragma unroll
      for (int r = 0; r < 4; ++r) {
        const int m = r0 + wm * 32 + im * 16 + crow + r;
        const float val = acc[im][in][r];
        if (p == 2) {
          vtmp[(size_t)m * DK + c] = val;
        } else {
          const unsigned short h = f2bf(val);
          const unsigned short lo2 = f2bf(val - bf2f(h));
          unsigned short* hd = p ? kh : qh;
          unsigned short* ld = p ? kl : ql;
          hd[(size_t)m * DK + c] = h;
          ld[(size_t)m * DK + c] = lo2;
        }
      }
    }
}

// ---------------------------------------------------------------------------
// Prep 3: transpose v fp32 [B][S][128] -> vT hi/lo bf16 [B][128][S]
// ---------------------------------------------------------------------------
__global__ __launch_bounds__(256) void cvtv_kernel(
    const float* __restrict__ v, unsigned short* __restrict__ vTh,
    unsigned short* __restrict__ vTl)
{
  const int s0 = blockIdx.x * 64, d0 = blockIdx.y * 64, b = blockIdx.z;
  __shared__ float Ts[64][65];
  const int t = threadIdx.x;
  const int r = t >> 4, c4 = (t & 15) * 4;
  #pragma unroll
  for (int rr = 0; rr < 4; ++rr) {
    const int sl = r + 16 * rr;
    *(float4*)&Ts[sl][c4] =
        *(const float4*)&v[((size_t)b * S + s0 + sl) * DK + d0 + c4];
  }
  __syncthreads();
  const int dl = t >> 2, sq = (t & 3) * 16;
  unsigned short hbuf[16], lbuf[16];
  #pragma unroll
  for (int j = 0; j < 16; ++j) {
    const float val = Ts[sq + j][dl];
    hbuf[j] = f2bf(val);
    lbuf[j] = f2bf(val - bf2f(hbuf[j]));
  }
  const size_t o = (size_t)b * DK * S + (size_t)(d0 + dl) * S + s0 + sq;
  #pragma unroll
  for (int half = 0; half < 2; ++half) {
    *(u16x8*)&vTh[o + half * 8] = *(u16x8*)&hbuf[half * 8];
    *(u16x8*)&vTl[o + half * 8] = *(u16x8*)&lbuf[half * 8];
  }
}

// ---------------------------------------------------------------------------
// Kernel B: column-softmax STATS ONLY. grid (NSP, 32, B); block (sp, qt)
// loops st = sp, sp+NSP, ... <= qt. Q staged once; K(st+NSP) prefetched
// after tile st's score MFMAs. 2 barriers/tile.
// ---------------------------------------------------------------------------
__global__ __launch_bounds__(256) void stats_mfma(
    const unsigned short* __restrict__ qh, const unsigned short* __restrict__ ql,
    const unsigned short* __restrict__ kh, const unsigned short* __restrict__ kl,
    float* __restrict__ pm, float* __restrict__ ps)
{
  const int sp = blockIdx.x, qt = blockIdx.y, b = blockIdx.z;
  if (sp > qt) return;
  const int q0 = qt * 64;

  __shared__ unsigned short Bsh[64 * 128], Bsl[64 * 128];   // Q stage / K
  __shared__ float SmL[64 * 2], SeL[64 * 2];

  const int t = threadIdx.x;
  const int l = t & 63, w = t >> 6;
  const int wm = w >> 1, wn = w & 1;
  const int fr = l & 15, kg = l >> 4;

  auto stage_K = [&](int s0k) {
    #pragma unroll
    for (int i = 0; i < 4; ++i) {
      const int flat = t + i * 256;
      const int row = flat >> 4, sg = flat & 15;
      const int sgs = sg ^ (row & 7);
      const size_t gk = (size_t)(b * S + s0k + row) * DK + sgs * 8;
      gload16(kh + gk, &Bsh[flat * 8]);
      gload16(kl + gk, &Bsl[flat * 8]);
    }
  };

  // ---- stage Q once, pull fragments to registers ----
  #pragma unroll
  for (int i = 0; i < 4; ++i) {
    const int flat = t + i * 256;
    const int row = flat >> 4, sg = flat & 15;
    const int sgs = sg ^ (row & 7);
    const size_t gq = (size_t)(b * S + q0 + row) * DK + sgs * 8;
    gload16(qh + gq, &Bsh[flat * 8]);
    gload16(ql + gq, &Bsl[flat * 8]);
  }
  __syncthreads();
  bf16x8 qfh[2][4], qfl[2][4];
  #pragma unroll
  for (int im = 0; im < 2; ++im)
    #pragma unroll
    for (int ks = 0; ks < 4; ++ks) {
      const int row = wm * 32 + im * 16 + fr;
      const int off = row * 128 + ((ks * 4 + kg) ^ (row & 7)) * 8;
      qfh[im][ks] = *(const bf16x8*)&Bsh[off];
      qfl[im][ks] = *(const bf16x8*)&Bsl[off];
    }
  __syncthreads();   // Q reads done before K overwrites

  stage_K(sp * 64);  // prologue: first K tile

  for (int st = sp; st <= qt; st += NSP) {
    const int s0 = st * 64;
    __syncthreads();   // drains K(st); orders prev SmL/SeL reuse

    // ---- scores (order must match fused_pv exactly) ----
    f32x4 sacc[2][2] = {};
    __builtin_amdgcn_s_setprio(1);
    #pragma unroll
    for (int ks = 0; ks < 4; ++ks) {
      bf16x8 bh[2], bl[2];
      #pragma unroll
      for (int in = 0; in < 2; ++in) {
        const int row = wn * 32 + in * 16 + fr;
        const int off = row * 128 + ((ks * 4 + kg) ^ (row & 7)) * 8;
        bh[in] = *(const bf16x8*)&Bsh[off];
        bl[in] = *(const bf16x8*)&Bsl[off];
      }
      #pragma unroll
      for (int im = 0; im < 2; ++im)
        #pragma unroll
        for (int in = 0; in < 2; ++in) {
          sacc[im][in] = __builtin_amdgcn_mfma_f32_16x16x32_bf16(qfh[im][ks], bh[in], sacc[im][in], 0, 0, 0);
          sacc[im][in] = __builtin_amdgcn_mfma_f32_16x16x32_bf16(qfh[im][ks], bl[in], sacc[im][in], 0, 0, 0);
          sacc[im][in] = __builtin_amdgcn_mfma_f32_16x16x32_bf16(qfl[im][ks], bh[in], sacc[im][in], 0, 0, 0);
        }
    }
    __builtin_amdgcn_s_setprio(0);

    // ---- prefetch next K tile (Ksh dead now; hides under stats VALU) ----
    if (st + NSP <= qt) stage_K((st + NSP) * 64);

    // ---- column stats (softmax over q within this 64-row chunk) ----
    const bool diag = (st == qt);
    float Sm_[2], Se_[2];
    #pragma unroll
    for (int in = 0; in < 2; ++in) {
      const int scol = s0 + wn * 32 + in * 16 + fr;
      float m8 = -INFINITY;
      #pragma unroll
      for (int im = 0; im < 2; ++im)
        #pragma unroll
        for (int r = 0; r < 4; ++r) {
          const int q = q0 + wm * 32 + im * 16 + kg * 4 + r;
          if (!diag || q >= scol) m8 = fmaxf(m8, sacc[im][in][r] * SCALE);
        }
      float e8 = 0.f;
      if (m8 > -INFINITY) {
        #pragma unroll
        for (int im = 0; im < 2; ++im)
          #pragma unroll
          for (int r = 0; r < 4; ++r) {
            const int q = q0 + wm * 32 + im * 16 + kg * 4 + r;
            if (!diag || q >= scol) e8 += __expf(sacc[im][in][r] * SCALE - m8);
          }
      }
      #pragma unroll
      for (int off = 16; off <= 32; off <<= 1) {
        const float om = __shfl_xor(m8, off);
        const float oe = __shfl_xor(e8, off);
        const float nm = fmaxf(m8, om);
        float ne = 0.f;
        if (m8 > -INFINITY) ne += e8 * __expf(m8 - nm);
        if (om > -INFINITY) ne += oe * __expf(om - nm);
        m8 = nm; e8 = ne;
      }
      Sm_[in] = m8; Se_[in] = e8;
    }
    if (l < 16) {
      #pragma unroll
      for (int in = 0; in < 2; ++in) {
        const int col = wn * 32 + in * 16 + l;
        SmL[col * 2 + wm] = Sm_[in];
        SeL[col * 2 + wm] = Se_[in];
      }
    }
    __syncthreads();
    if (t < 64) {
      const float m0 = SmL[t * 2 + 0], m1 = SmL[t * 2 + 1];
      const float nm = fmaxf(m0, m1);
      float ne = 0.f;
      if (m0 > -INFINITY) ne += SeL[t * 2 + 0] * __expf(m0 - nm);
      if (m1 > -INFINITY) ne += SeL[t * 2 + 1] * __expf(m1 - nm);
      const size_t o = ((size_t)(b * 32 + qt)) * S + s0 + t;
      pm[o] = nm;
      ps[o] = ne;
    }
    // loop-top barrier orders SmL reuse + drains prefetched K
  }
}

// ---------------------------------------------------------------------------
// Kernel C: combine 32 row-chunk partials -> per-column max m and 1/sum.
// ---------------------------------------------------------------------------
__global__ void colcombine_kernel(const float* __restrict__ pm, const float* __restrict__ ps,
                                  float* __restrict__ cm, float* __restrict__ cinv)
{
  const int s = blockIdx.x * 256 + threadIdx.x;
  const int b = blockIdx.y;
  const int ch0 = s >> 6;
  float m = -INFINITY;
  for (int ch = ch0; ch < 32; ++ch)
    m = fmaxf(m, pm[((size_t)(b * 32 + ch)) * S + s]);
  float sum = 0.f;
  for (int ch = ch0; ch < 32; ++ch) {
    const size_t i = ((size_t)(b * 32 + ch)) * S + s;
    sum += ps[i] * __expf(pm[i] - m);
  }
  cm[(size_t)b * S + s]   = m;
  cinv[(size_t)b * S + s] = 1.f / sum;   // sum >= 1 (diagonal element)
}

// ---------------------------------------------------------------------------
// zero out (out is atomically accumulated)
// ---------------------------------------------------------------------------
__global__ void zero_out_kernel(float* __restrict__ out)
{
  const size_t idx = (size_t)blockIdx.x * 256 + threadIdx.x;
  ((float4*)out)[idx] = float4{0.f, 0.f, 0.f, 0.f};
}

// ---------------------------------------------------------------------------
// Kernel D: fused second pass. grid (NSP_PV, 32, B) = 512 blocks (488
// active) — exactly ONE co-resident generation at 2 blocks/CU (72 KB LDS):
// no generation-boundary tail, ~8.7 tiles/block so the K-prefetch /
// deferred-store pipeline amortizes 2x better (round-19 lever). One atomic
// epilogue per block (4-way contention). Scores recomputed
// bitwise-identical to stats_mfma.
// ---------------------------------------------------------------------------
__global__ __launch_bounds__(256) void fused_pv(
    const unsigned short* __restrict__ qh, const unsigned short* __restrict__ ql,
    const unsigned short* __restrict__ kh, const unsigned short* __restrict__ kl,
    const unsigned short* __restrict__ vTh, const unsigned short* __restrict__ vTl,
    const float* __restrict__ cm, const float* __restrict__ cinv,
    float* __restrict__ att, float* __restrict__ out)
{
  const int sp = blockIdx.x, qt = blockIdx.y, b = blockIdx.z;
  if (sp > qt) return;
  const int q0 = qt * 64;
  float* attb = att + (size_t)b * S * S;
  const unsigned short* vth = vTh + (size_t)b * DK * S;
  const unsigned short* vtl = vTl + (size_t)b * DK * S;

  __shared__ unsigned short Ksh[64 * 128], Ksl[64 * 128];   // Q stage / K (32 KB)
  __shared__ unsigned short Vsh[128 * 64], Vsl[128 * 64];   // vT tile (32 KB)
  __shared__ unsigned short Psh[64 * 64];                   // P tile (8 KB)

  const int t = threadIdx.x;
  const int l = t & 63, w = t >> 6;
  const int wm = w >> 1, wn = w & 1;          // 2x2 wave grid (scores)
  const int fr = l & 15, kg = l >> 4;

  auto stage_K = [&](int s0k) {
    #pragma unroll
    for (int i = 0; i < 4; ++i) {
      const int flat = t + i * 256;
      const int row = flat >> 4, sg = flat & 15;
      const int sgs = sg ^ (row & 7);
      const size_t gk = (size_t)(b * S + s0k + row) * DK + sgs * 8;
      gload16(kh + gk, &Ksh[flat * 8]);
      gload16(kl + gk, &Ksl[flat * 8]);
    }
  };

  // ---- stage Q tile once, pull fragments to registers ----
  #pragma unroll
  for (int i = 0; i < 4; ++i) {
    const int flat = t + i * 256;
    const int row = flat >> 4, sg = flat & 15;
    const int sgs = sg ^ (row & 7);
    const size_t gq = (size_t)(b * S + q0 + row) * DK + sgs * 8;
    gload16(qh + gq, &Ksh[flat * 8]);
    gload16(ql + gq, &Ksl[flat * 8]);
  }
  __syncthreads();
  bf16x8 qfh[2][4], qfl[2][4];
  #pragma unroll
  for (int im = 0; im < 2; ++im)
    #pragma unroll
    for (int ks = 0; ks < 4; ++ks) {
      const int row = wm * 32 + im * 16 + fr;
      const int off = row * 128 + ((ks * 4 + kg) ^ (row & 7)) * 8;
      qfh[im][ks] = *(const bf16x8*)&Ksh[off];
      qfl[im][ks] = *(const bf16x8*)&Ksl[off];
    }
  __syncthreads();   // all Q reads done before K overwrites

  stage_K(sp * 64);  // prologue: first K tile

  f32x4 acc[8] = {};     // PV accumulator, persists across st tiles
  float xv[2][2][4];     // previous tile's normalized att values
  int prev_s0 = -1;
  int prev_mirror = 0;

  for (int st = sp; st <= qt; st += NSP_PV) {
    const int s0 = st * 64;

    // ---- stage V tile (issue) ----
    #pragma unroll
    for (int i = 0; i < 4; ++i) {
      const int flat = t + i * 256;
      const int row = flat >> 3, sg = flat & 7;
      const int sgs = sg ^ (row & 7);
      const size_t gv = (size_t)row * S + s0 + sgs * 8;
      gload16(vth + gv, &Vsh[flat * 8]);
      gload16(vtl + gv, &Vsl[flat * 8]);
    }

    // ---- deferred att/mirror stores for the PREVIOUS tile (load shadow) ----
    if (prev_s0 >= 0) {
      if (prev_mirror) {
        const f32x4 z = {0.f, 0.f, 0.f, 0.f};
        #pragma unroll
        for (int i = 0; i < 4; ++i) {
          const int flat = t + i * 256;
          const int row = flat >> 4, c4 = (flat & 15) * 4;
          __builtin_nontemporal_store(z, (f32x4*)&attb[(size_t)(prev_s0 + row) * S + q0 + c4]);
        }
      }
      #pragma unroll
      for (int im = 0; im < 2; ++im)
        #pragma unroll
        for (int in = 0; in < 2; ++in) {
          const int sloc = wn * 32 + in * 16 + fr;
          #pragma unroll
          for (int r = 0; r < 4; ++r) {
            const int qloc = wm * 32 + im * 16 + kg * 4 + r;
            __builtin_nontemporal_store(xv[im][in][r],
                                        &attb[(size_t)(q0 + qloc) * S + prev_s0 + sloc]);
          }
        }
    }
    __syncthreads();   // joint drain: K(st) [prefetched] + V loads + stores

    // ---- scores: identical accumulation order to stats_mfma ----
    f32x4 sacc[2][2] = {};
    __builtin_amdgcn_s_setprio(1);
    #pragma unroll
    for (int ks = 0; ks < 4; ++ks) {
      bf16x8 bh[2], bl[2];
      #pragma unroll
      for (int in = 0; in < 2; ++in) {
        const int row = wn * 32 + in * 16 + fr;
        const int off = row * 128 + ((ks * 4 + kg) ^ (row & 7)) * 8;
        bh[in] = *(const bf16x8*)&Ksh[off];
        bl[in] = *(const bf16x8*)&Ksl[off];
      }
      #pragma unroll
      for (int im = 0; im < 2; ++im)
        #pragma unroll
        for (int in = 0; in < 2; ++in) {
          sacc[im][in] = __builtin_amdgcn_mfma_f32_16x16x32_bf16(qfh[im][ks], bh[in], sacc[im][in], 0, 0, 0);
          sacc[im][in] = __builtin_amdgcn_mfma_f32_16x16x32_bf16(qfh[im][ks], bl[in], sacc[im][in], 0, 0, 0);
          sacc[im][in] = __builtin_amdgcn_mfma_f32_16x16x32_bf16(qfl[im][ks], bh[in], sacc[im][in], 0, 0, 0);
        }
    }
    __builtin_amdgcn_s_setprio(0);

    // ---- normalize in-register; P (plain bf16) -> LDS; keep xv in regs ----
    const bool diag = (st == qt);
    #pragma unroll
    for (int in = 0; in < 2; ++in) {
      const int sloc = wn * 32 + in * 16 + fr;
      const int scol = s0 + sloc;
      const float m   = cm[(size_t)b * S + scol];
      const float inv = cinv[(size_t)b * S + scol];
      #pragma unroll
      for (int im = 0; im < 2; ++im) {
        #pragma unroll
        for (int r = 0; r < 4; ++r) {
          const int qloc = wm * 32 + im * 16 + kg * 4 + r;
          const bool live = !diag || (q0 + qloc >= scol);
          const float x = live ? __expf(sacc[im][in][r] * SCALE - m) * inv : 0.f;
          xv[im][in][r] = x;
          const int idx = qloc * 64 + (((sloc >> 3) ^ (qloc & 7)) * 8 + (sloc & 7));
          Psh[idx] = f2bf(x);
        }
      }
    }
    __syncthreads();   // P visible; Ksh now dead

    // ---- prefetch next K tile into Ksh (hides under PV) ----
    if (st + NSP_PV <= qt) stage_K((st + NSP_PV) * 64);

    // ---- PV: wave w computes q rows [w*16, w*16+16), all 128 d cols ----
    __builtin_amdgcn_s_setprio(1);
    #pragma unroll
    for (int ks2 = 0; ks2 < 2; ++ks2) {
      const int arow = w * 16 + fr;
      const int aoff = arow * 64 + ((ks2 * 4 + kg) ^ (arow & 7)) * 8;
      const bf16x8 a = *(const bf16x8*)&Psh[aoff];
      #pragma unroll
      for (int in = 0; in < 8; ++in) {
        const int brow = in * 16 + fr;
        const int boff = brow * 64 + ((ks2 * 4 + kg) ^ (brow & 7)) * 8;
        const bf16x8 b_h = *(const bf16x8*)&Vsh[boff];
        const bf16x8 b_l = *(const bf16x8*)&Vsl[boff];
        acc[in] = __builtin_amdgcn_mfma_f32_16x16x32_bf16(a, b_h, acc[in], 0, 0, 0);
        acc[in] = __builtin_amdgcn_mfma_f32_16x16x32_bf16(a, b_l, acc[in], 0, 0, 0);
      }
    }
    __builtin_amdgcn_s_setprio(0);
    __syncthreads();   // Vsh/Psh reads done before next-iter V staging

    prev_s0 = s0;
    prev_mirror = (st < qt) ? 1 : 0;
  }

  // ---- final tile's deferred stores ----
  if (prev_s0 >= 0) {
    if (prev_mirror) {
      const f32x4 z = {0.f, 0.f, 0.f, 0.f};
      #pragma unroll
      for (int i = 0; i < 4; ++i) {
        const int flat = t + i * 256;
        const int row = flat >> 4, c4 = (flat & 15) * 4;
        __builtin_nontemporal_store(z, (f32x4*)&attb[(size_t)(prev_s0 + row) * S + q0 + c4]);
      }
    }
    #pragma unroll
    for (int im = 0; im < 2; ++im)
      #pragma unroll
      for (int in = 0; in < 2; ++in) {
        const int sloc = wn * 32 + in * 16 + fr;
        #pragma unroll
        for (int r = 0; r < 4; ++r) {
          const int qloc = wm * 32 + im * 16 + kg * 4 + r;
          __builtin_nontemporal_store(xv[im][in][r],
                                      &attb[(size_t)(q0 + qloc) * S + prev_s0 + sloc]);
        }
      }
  }

  // ---- single atomic epilogue per block ----
  #pragma unroll
  for (int in = 0; in < 8; ++in) {
    #pragma unroll
    for (int r = 0; r < 4; ++r) {
      const int q = q0 + w * 16 + kg * 4 + r;
      const int d = in * 16 + fr;
      atomicAdd(&out[((size_t)b * S + q) * DK + d], acc[in][r]);
    }
  }
}

// ---------------------------------------------------------------------------
extern "C" void kernel_launch(void* const* d_in, const int* in_sizes, int n_in,
                              void* d_out, int out_size, void* d_ws, size_t ws_size,
                              hipStream_t stream)
{
  const float* vin = (const float*)d_in[0];
  const float* wq  = (const float*)d_in[1];
  const float* wk  = (const float*)d_in[2];
  const float* wv  = (const float*)d_in[3];

  float* out = (float*)d_out;
  float* att = out + (size_t)B * S * DK;     // attention output region (64 MB)

  // bf16 copies of vin / W live INSIDE the att region (dead before att writes)
  unsigned short* Ah  = (unsigned short*)att;
  unsigned short* Al  = Ah  + (size_t)BS * DM;
  unsigned short* Wth = Al  + (size_t)BS * DM;
  unsigned short* Wtl = Wth + (size_t)384 * DM;

  constexpr size_t NE = (size_t)BS * DK;     // 1048576
  unsigned short* qh  = (unsigned short*)d_ws;
  unsigned short* ql  = qh  + NE;
  unsigned short* kh  = ql  + NE;
  unsigned short* kl  = kh  + NE;
  unsigned short* vTh = kl  + NE;
  unsigned short* vTl = vTh + NE;
  float* vtmp = (float*)(vTl + NE);          // 4 MB
  float* pm   = vtmp;                        // aliases vtmp (v dead by then)
  float* ps   = pm + 32ull * B * S;          // 1 MB each
  float* cm   = ps + 32ull * B * S;
  float* cinv = cm + (size_t)B * S;

  cvt_hilo         <<<dim3(BS * DM / 1024),  256, 0, stream>>>(vin, Ah, Al);
  cvtw_kernel      <<<dim3(384),             256, 0, stream>>>(wq, wk, wv, Wth, Wtl);
  proj_mfma        <<<dim3(BS / 64, 6),      256, 0, stream>>>(Ah, Al, Wth, Wtl,
                                                               qh, ql, kh, kl, vtmp);
  cvtv_kernel      <<<dim3(S / 64, 2, B),    256, 0, stream>>>(vtmp, vTh, vTl);
  zero_out_kernel  <<<dim3(BS * DK / 1024),  256, 0, stream>>>(out);
  stats_mfma       <<<dim3(NSP, 32, B),      256, 0, stream>>>(qh, ql, kh, kl, pm, ps);
  colcombine_kernel<<<dim3(S / 256, B),      256, 0, stream>>>(pm, ps, cm, cinv);
  fused_pv         <<<dim3(NSP_PV, 32, B),   256, 0, stream>>>(qh, ql, kh, kl, vTh, vTl,
                                                               cm, cinv, att, out);
}

// Round 20
// 109.156 us; speedup vs baseline: 1.0889x; 1.0532x over previous
//
#include <hip/hip_runtime.h>
#include <math.h>

// Problem constants
constexpr int B  = 4;
constexpr int S  = 2048;
constexpr int DM = 1024;
constexpr int DK = 128;
constexpr int BS = B * S;
constexpr int NSP    = 8;   // st-split factor for stats
constexpr int NSP_PV = 4;   // st-split for fused_pv (one resident generation)

static constexpr float SCALE = 0.08838834764831845f; // 1/sqrt(128)

typedef __attribute__((ext_vector_type(8))) short bf16x8;
typedef __attribute__((ext_vector_type(4))) float f32x4;
typedef __attribute__((ext_vector_type(8))) unsigned short u16x8;

__device__ __forceinline__ unsigned short f2bf(float x) {
  unsigned u = __float_as_uint(x);
  unsigned r = (u + 0x7FFFu + ((u >> 16) & 1u)) >> 16;   // RNE
  return (unsigned short)r;
}
__device__ __forceinline__ unsigned short f2bf_tr(float x) {
  return (unsigned short)(__float_as_uint(x) >> 16);      // truncate
}
__device__ __forceinline__ float bf2f(unsigned short h) {
  return __uint_as_float(((unsigned)h) << 16);
}

__device__ __forceinline__ void gload16(const void* g, void* l) {
  __builtin_amdgcn_global_load_lds(
      (const __attribute__((address_space(1))) void*)g,
      (__attribute__((address_space(3))) void*)l, 16, 0, 0);
}

// ---------------------------------------------------------------------------
// Prep: w_q/w_k/w_v [1024][128] fp32 -> Wt hi/lo bf16 [384][1024] (B^T)
// ---------------------------------------------------------------------------
__global__ void cvtw_kernel(const float* __restrict__ wq, const float* __restrict__ wk,
                            const float* __restrict__ wv,
                            unsigned short* __restrict__ Wth, unsigned short* __restrict__ Wtl)
{
  const int n = blockIdx.x;            // 0..383
  const int p = n >> 7, c = n & 127;
  const float* w = (p == 0) ? wq : (p == 1) ? wk : wv;
  for (int k = threadIdx.x; k < DM; k += 256) {
    const float x = w[(size_t)k * DK + c];
    const unsigned short h = f2bf(x);
    Wth[(size_t)n * DM + k] = h;
    Wtl[(size_t)n * DM + k] = f2bf(x - bf2f(h));
  }
}

// ---------------------------------------------------------------------------
// Kernel A: projections via split-bf16 MFMA. A is staged DIRECTLY from vin
// (fp32): load float4, split hi/lo in-register (truncation split — the pair
// represents val to ~2^-16 regardless of hi rounding), swizzled ds_write.
// This removes the former cvt_hilo kernel (64 MB HBM round trip).
// W staged via gload_lds from the cvtw output (unchanged).
// ---------------------------------------------------------------------------
__global__ __launch_bounds__(256) void proj_mfma(
    const float* __restrict__ vin,
    const unsigned short* __restrict__ Wh, const unsigned short* __restrict__ Wl,
    unsigned short* __restrict__ qh, unsigned short* __restrict__ ql,
    unsigned short* __restrict__ kh, unsigned short* __restrict__ kl,
    float* __restrict__ vtmp)
{
  __shared__ unsigned short Ash[2][64 * 64];
  __shared__ unsigned short Wsh[2][64 * 64];

  const int r0 = blockIdx.x * 64;      // M tile
  const int n0 = blockIdx.y * 64;      // N tile (384/64 = 6)
  const int t  = threadIdx.x;
  const int l  = t & 63, w = t >> 6;
  const int wm = w >> 1, wn = w & 1;   // 2x2 wave grid
  const int fr = l & 15, kg = l >> 4;  // fragment row / k-group

  f32x4 acc[2][2] = {};

  for (int k0 = 0; k0 < DM; k0 += 64) {
    // ---- stage W 64x64 hi/lo via gload_lds (pre-swizzled source) ----
    #pragma unroll
    for (int i = 0; i < 2; ++i) {
      const int flat = t + i * 256;          // 512 16B segments per buffer
      const int row = flat >> 3, sg = flat & 7;
      const int sgs = sg ^ (row & 7);
      const size_t gw = (size_t)(n0 + row) * DM + k0 + sgs * 8;
      gload16(Wh + gw, &Wsh[0][flat * 8]);
      gload16(Wl + gw, &Wsh[1][flat * 8]);
    }
    // ---- stage A 64x64 from vin fp32: convert + swizzled ds_write ----
    #pragma unroll
    for (int i = 0; i < 4; ++i) {
      const int flat = t + i * 256;          // 0..1023 float4 slots
      const int row = flat >> 4;
      const int c4  = (flat & 15) * 4;
      const float4 a = *(const float4*)&vin[(size_t)(r0 + row) * DM + k0 + c4];
      ushort4 h, lo4;
      h.x = f2bf_tr(a.x); lo4.x = f2bf_tr(a.x - bf2f(h.x));
      h.y = f2bf_tr(a.y); lo4.y = f2bf_tr(a.y - bf2f(h.y));
      h.z = f2bf_tr(a.z); lo4.z = f2bf_tr(a.z - bf2f(h.z));
      h.w = f2bf_tr(a.w); lo4.w = f2bf_tr(a.w - bf2f(h.w));
      const int off = row * 64 + (((c4 >> 3) ^ (row & 7)) * 8) + (c4 & 7);
      *(ushort4*)&Ash[0][off] = h;
      *(ushort4*)&Ash[1][off] = lo4;
    }
    __syncthreads();

    __builtin_amdgcn_s_setprio(1);
    #pragma unroll
    for (int kk = 0; kk < 2; ++kk) {
      bf16x8 ah[2], al[2], bh[2], bl[2];
      #pragma unroll
      for (int im = 0; im < 2; ++im) {
        const int row = wm * 32 + im * 16 + fr;
        const int off = row * 64 + ((kk * 4 + kg) ^ (row & 7)) * 8;
        ah[im] = *(const bf16x8*)&Ash[0][off];
        al[im] = *(const bf16x8*)&Ash[1][off];
      }
      #pragma unroll
      for (int in = 0; in < 2; ++in) {
        const int row = wn * 32 + in * 16 + fr;
        const int off = row * 64 + ((kk * 4 + kg) ^ (row & 7)) * 8;
        bh[in] = *(const bf16x8*)&Wsh[0][off];
        bl[in] = *(const bf16x8*)&Wsh[1][off];
      }
      #pragma unroll
      for (int im = 0; im < 2; ++im)
        #pragma unroll
        for (int in = 0; in < 2; ++in) {
          acc[im][in] = __builtin_amdgcn_mfma_f32_16x16x32_bf16(ah[im], bh[in], acc[im][in], 0, 0, 0);
          acc[im][in] = __builtin_amdgcn_mfma_f32_16x16x32_bf16(ah[im], bl[in], acc[im][in], 0, 0, 0);
          acc[im][in] = __builtin_amdgcn_mfma_f32_16x16x32_bf16(al[im], bh[in], acc[im][in], 0, 0, 0);
        }
    }
    __builtin_amdgcn_s_setprio(0);
    __syncthreads();
  }

  // Epilogue: C/D layout col = lane&15, row = (lane>>4)*4 + reg
  const int crow = kg * 4;
  #pragma unroll
  for (int im = 0; im < 2; ++im)
    #pragma unroll
    for (int in = 0; in < 2; ++in) {
      const int n = n0 + wn * 32 + in * 16 + fr;
      const int p = n >> 7, c = n & 127;           // p uniform per block
      #pragma unroll
      for (int r = 0; r < 4; ++r) {
        const int m = r0 + wm * 32 + im * 16 + crow + r;
        const float val = acc[im][in][r];
        if (p == 2) {
          vtmp[(size_t)m * DK + c] = val;
        } else {
          const unsigned short h = f2bf(val);
          const unsigned short lo2 = f2bf(val - bf2f(h));
          unsigned short* hd = p ? kh : qh;
          unsigned short* ld = p ? kl : ql;
          hd[(size_t)m * DK + c] = h;
          ld[(size_t)m * DK + c] = lo2;
        }
      }
    }
}

// ---------------------------------------------------------------------------
// Prep 3: transpose v fp32 [B][S][128] -> vT hi/lo bf16 [B][128][S]
// ---------------------------------------------------------------------------
__global__ __launch_bounds__(256) void cvtv_kernel(
    const float* __restrict__ v, unsigned short* __restrict__ vTh,
    unsigned short* __restrict__ vTl)
{
  const int s0 = blockIdx.x * 64, d0 = blockIdx.y * 64, b = blockIdx.z;
  __shared__ float Ts[64][65];
  const int t = threadIdx.x;
  const int r = t >> 4, c4 = (t & 15) * 4;
  #pragma unroll
  for (int rr = 0; rr < 4; ++rr) {
    const int sl = r + 16 * rr;
    *(float4*)&Ts[sl][c4] =
        *(const float4*)&v[((size_t)b * S + s0 + sl) * DK + d0 + c4];
  }
  __syncthreads();
  const int dl = t >> 2, sq = (t & 3) * 16;
  unsigned short hbuf[16], lbuf[16];
  #pragma unroll
  for (int j = 0; j < 16; ++j) {
    const float val = Ts[sq + j][dl];
    hbuf[j] = f2bf(val);
    lbuf[j] = f2bf(val - bf2f(hbuf[j]));
  }
  const size_t o = (size_t)b * DK * S + (size_t)(d0 + dl) * S + s0 + sq;
  #pragma unroll
  for (int half = 0; half < 2; ++half) {
    *(u16x8*)&vTh[o + half * 8] = *(u16x8*)&hbuf[half * 8];
    *(u16x8*)&vTl[o + half * 8] = *(u16x8*)&lbuf[half * 8];
  }
}

// ---------------------------------------------------------------------------
// Kernel B: column-softmax STATS ONLY. grid (NSP, 32, B); block (sp, qt)
// loops st = sp, sp+NSP, ... <= qt. Q staged once; K(st+NSP) prefetched
// after tile st's score MFMAs. 2 barriers/tile.
// ---------------------------------------------------------------------------
__global__ __launch_bounds__(256) void stats_mfma(
    const unsigned short* __restrict__ qh, const unsigned short* __restrict__ ql,
    const unsigned short* __restrict__ kh, const unsigned short* __restrict__ kl,
    float* __restrict__ pm, float* __restrict__ ps)
{
  const int sp = blockIdx.x, qt = blockIdx.y, b = blockIdx.z;
  if (sp > qt) return;
  const int q0 = qt * 64;

  __shared__ unsigned short Bsh[64 * 128], Bsl[64 * 128];   // Q stage / K
  __shared__ float SmL[64 * 2], SeL[64 * 2];

  const int t = threadIdx.x;
  const int l = t & 63, w = t >> 6;
  const int wm = w >> 1, wn = w & 1;
  const int fr = l & 15, kg = l >> 4;

  auto stage_K = [&](int s0k) {
    #pragma unroll
    for (int i = 0; i < 4; ++i) {
      const int flat = t + i * 256;
      const int row = flat >> 4, sg = flat & 15;
      const int sgs = sg ^ (row & 7);
      const size_t gk = (size_t)(b * S + s0k + row) * DK + sgs * 8;
      gload16(kh + gk, &Bsh[flat * 8]);
      gload16(kl + gk, &Bsl[flat * 8]);
    }
  };

  // ---- stage Q once, pull fragments to registers ----
  #pragma unroll
  for (int i = 0; i < 4; ++i) {
    const int flat = t + i * 256;
    const int row = flat >> 4, sg = flat & 15;
    const int sgs = sg ^ (row & 7);
    const size_t gq = (size_t)(b * S + q0 + row) * DK + sgs * 8;
    gload16(qh + gq, &Bsh[flat * 8]);
    gload16(ql + gq, &Bsl[flat * 8]);
  }
  __syncthreads();
  bf16x8 qfh[2][4], qfl[2][4];
  #pragma unroll
  for (int im = 0; im < 2; ++im)
    #pragma unroll
    for (int ks = 0; ks < 4; ++ks) {
      const int row = wm * 32 + im * 16 + fr;
      const int off = row * 128 + ((ks * 4 + kg) ^ (row & 7)) * 8;
      qfh[im][ks] = *(const bf16x8*)&Bsh[off];
      qfl[im][ks] = *(const bf16x8*)&Bsl[off];
    }
  __syncthreads();   // Q reads done before K overwrites

  stage_K(sp * 64);  // prologue: first K tile

  for (int st = sp; st <= qt; st += NSP) {
    const int s0 = st * 64;
    __syncthreads();   // drains K(st); orders prev SmL/SeL reuse

    // ---- scores (order must match fused_pv exactly) ----
    f32x4 sacc[2][2] = {};
    __builtin_amdgcn_s_setprio(1);
    #pragma unroll
    for (int ks = 0; ks < 4; ++ks) {
      bf16x8 bh[2], bl[2];
      #pragma unroll
      for (int in = 0; in < 2; ++in) {
        const int row = wn * 32 + in * 16 + fr;
        const int off = row * 128 + ((ks * 4 + kg) ^ (row & 7)) * 8;
        bh[in] = *(const bf16x8*)&Bsh[off];
        bl[in] = *(const bf16x8*)&Bsl[off];
      }
      #pragma unroll
      for (int im = 0; im < 2; ++im)
        #pragma unroll
        for (int in = 0; in < 2; ++in) {
          sacc[im][in] = __builtin_amdgcn_mfma_f32_16x16x32_bf16(qfh[im][ks], bh[in], sacc[im][in], 0, 0, 0);
          sacc[im][in] = __builtin_amdgcn_mfma_f32_16x16x32_bf16(qfh[im][ks], bl[in], sacc[im][in], 0, 0, 0);
          sacc[im][in] = __builtin_amdgcn_mfma_f32_16x16x32_bf16(qfl[im][ks], bh[in], sacc[im][in], 0, 0, 0);
        }
    }
    __builtin_amdgcn_s_setprio(0);

    // ---- prefetch next K tile (Bsh dead now; hides under stats VALU) ----
    if (st + NSP <= qt) stage_K((st + NSP) * 64);

    // ---- column stats (softmax over q within this 64-row chunk) ----
    const bool diag = (st == qt);
    float Sm_[2], Se_[2];
    #pragma unroll
    for (int in = 0; in < 2; ++in) {
      const int scol = s0 + wn * 32 + in * 16 + fr;
      float m8 = -INFINITY;
      #pragma unroll
      for (int im = 0; im < 2; ++im)
        #pragma unroll
        for (int r = 0; r < 4; ++r) {
          const int q = q0 + wm * 32 + im * 16 + kg * 4 + r;
          if (!diag || q >= scol) m8 = fmaxf(m8, sacc[im][in][r] * SCALE);
        }
      float e8 = 0.f;
      if (m8 > -INFINITY) {
        #pragma unroll
        for (int im = 0; im < 2; ++im)
          #pragma unroll
          for (int r = 0; r < 4; ++r) {
            const int q = q0 + wm * 32 + im * 16 + kg * 4 + r;
            if (!diag || q >= scol) e8 += __expf(sacc[im][in][r] * SCALE - m8);
          }
      }
      #pragma unroll
      for (int off = 16; off <= 32; off <<= 1) {
        const float om = __shfl_xor(m8, off);
        const float oe = __shfl_xor(e8, off);
        const float nm = fmaxf(m8, om);
        float ne = 0.f;
        if (m8 > -INFINITY) ne += e8 * __expf(m8 - nm);
        if (om > -INFINITY) ne += oe * __expf(om - nm);
        m8 = nm; e8 = ne;
      }
      Sm_[in] = m8; Se_[in] = e8;
    }
    if (l < 16) {
      #pragma unroll
      for (int in = 0; in < 2; ++in) {
        const int col = wn * 32 + in * 16 + l;
        SmL[col * 2 + wm] = Sm_[in];
        SeL[col * 2 + wm] = Se_[in];
      }
    }
    __syncthreads();
    if (t < 64) {
      const float m0 = SmL[t * 2 + 0], m1 = SmL[t * 2 + 1];
      const float nm = fmaxf(m0, m1);
      float ne = 0.f;
      if (m0 > -INFINITY) ne += SeL[t * 2 + 0] * __expf(m0 - nm);
      if (m1 > -INFINITY) ne += SeL[t * 2 + 1] * __expf(m1 - nm);
      const size_t o = ((size_t)(b * 32 + qt)) * S + s0 + t;
      pm[o] = nm;
      ps[o] = ne;
    }
    // loop-top barrier orders SmL reuse + drains prefetched K
  }
}

// ---------------------------------------------------------------------------
// Kernel C: combine 32 row-chunk partials -> per-column max m and 1/sum.
// ---------------------------------------------------------------------------
__global__ void colcombine_kernel(const float* __restrict__ pm, const float* __restrict__ ps,
                                  float* __restrict__ cm, float* __restrict__ cinv)
{
  const int s = blockIdx.x * 256 + threadIdx.x;
  const int b = blockIdx.y;
  const int ch0 = s >> 6;
  float m = -INFINITY;
  for (int ch = ch0; ch < 32; ++ch)
    m = fmaxf(m, pm[((size_t)(b * 32 + ch)) * S + s]);
  float sum = 0.f;
  for (int ch = ch0; ch < 32; ++ch) {
    const size_t i = ((size_t)(b * 32 + ch)) * S + s;
    sum += ps[i] * __expf(pm[i] - m);
  }
  cm[(size_t)b * S + s]   = m;
  cinv[(size_t)b * S + s] = 1.f / sum;   // sum >= 1 (diagonal element)
}

// ---------------------------------------------------------------------------
// zero out (out is atomically accumulated)
// ---------------------------------------------------------------------------
__global__ void zero_out_kernel(float* __restrict__ out)
{
  const size_t idx = (size_t)blockIdx.x * 256 + threadIdx.x;
  ((float4*)out)[idx] = float4{0.f, 0.f, 0.f, 0.f};
}

// ---------------------------------------------------------------------------
// Kernel D: fused second pass. grid (NSP_PV, 32, B) = 488 active blocks —
// one co-resident generation at 2 blocks/CU. Pipeline: V(st) issued at top
// with prev tile's deferred att/mirror stores in its shadow; K(st+NSP_PV)
// issued after the P-visible barrier so its latency hides under PV. One
// atomic epilogue per block. Scores recomputed bitwise-identical to
// stats_mfma. LDS 72 KB.
// ---------------------------------------------------------------------------
__global__ __launch_bounds__(256) void fused_pv(
    const unsigned short* __restrict__ qh, const unsigned short* __restrict__ ql,
    const unsigned short* __restrict__ kh, const unsigned short* __restrict__ kl,
    const unsigned short* __restrict__ vTh, const unsigned short* __restrict__ vTl,
    const float* __restrict__ cm, const float* __restrict__ cinv,
    float* __restrict__ att, float* __restrict__ out)
{
  const int sp = blockIdx.x, qt = blockIdx.y, b = blockIdx.z;
  if (sp > qt) return;
  const int q0 = qt * 64;
  float* attb = att + (size_t)b * S * S;
  const unsigned short* vth = vTh + (size_t)b * DK * S;
  const unsigned short* vtl = vTl + (size_t)b * DK * S;

  __shared__ unsigned short Ksh[64 * 128], Ksl[64 * 128];   // Q stage / K (32 KB)
  __shared__ unsigned short Vsh[128 * 64], Vsl[128 * 64];   // vT tile (32 KB)
  __shared__ unsigned short Psh[64 * 64];                   // P tile (8 KB)

  const int t = threadIdx.x;
  const int l = t & 63, w = t >> 6;
  const int wm = w >> 1, wn = w & 1;          // 2x2 wave grid (scores)
  const int fr = l & 15, kg = l >> 4;

  auto stage_K = [&](int s0k) {
    #pragma unroll
    for (int i = 0; i < 4; ++i) {
      const int flat = t + i * 256;
      const int row = flat >> 4, sg = flat & 15;
      const int sgs = sg ^ (row & 7);
      const size_t gk = (size_t)(b * S + s0k + row) * DK + sgs * 8;
      gload16(kh + gk, &Ksh[flat * 8]);
      gload16(kl + gk, &Ksl[flat * 8]);
    }
  };

  // ---- stage Q tile once, pull fragments to registers ----
  #pragma unroll
  for (int i = 0; i < 4; ++i) {
    const int flat = t + i * 256;
    const int row = flat >> 4, sg = flat & 15;
    const int sgs = sg ^ (row & 7);
    const size_t gq = (size_t)(b * S + q0 + row) * DK + sgs * 8;
    gload16(qh + gq, &Ksh[flat * 8]);
    gload16(ql + gq, &Ksl[flat * 8]);
  }
  __syncthreads();
  bf16x8 qfh[2][4], qfl[2][4];
  #pragma unroll
  for (int im = 0; im < 2; ++im)
    #pragma unroll
    for (int ks = 0; ks < 4; ++ks) {
      const int row = wm * 32 + im * 16 + fr;
      const int off = row * 128 + ((ks * 4 + kg) ^ (row & 7)) * 8;
      qfh[im][ks] = *(const bf16x8*)&Ksh[off];
      qfl[im][ks] = *(const bf16x8*)&Ksl[off];
    }
  __syncthreads();   // all Q reads done before K overwrites

  stage_K(sp * 64);  // prologue: first K tile

  f32x4 acc[8] = {};     // PV accumulator, persists across st tiles
  float xv[2][2][4];     // previous tile's normalized att values
  int prev_s0 = -1;
  int prev_mirror = 0;

  for (int st = sp; st <= qt; st += NSP_PV) {
    const int s0 = st * 64;

    // ---- stage V tile (issue) ----
    #pragma unroll
    for (int i = 0; i < 4; ++i) {
      const int flat = t + i * 256;
      const int row = flat >> 3, sg = flat & 7;
      const int sgs = sg ^ (row & 7);
      const size_t gv = (size_t)row * S + s0 + sgs * 8;
      gload16(vth + gv, &Vsh[flat * 8]);
      gload16(vtl + gv, &Vsl[flat * 8]);
    }

    // ---- deferred att/mirror stores for the PREVIOUS tile (load shadow) ----
    if (prev_s0 >= 0) {
      if (prev_mirror) {
        const f32x4 z = {0.f, 0.f, 0.f, 0.f};
        #pragma unroll
        for (int i = 0; i < 4; ++i) {
          const int flat = t + i * 256;
          const int row = flat >> 4, c4 = (flat & 15) * 4;
          __builtin_nontemporal_store(z, (f32x4*)&attb[(size_t)(prev_s0 + row) * S + q0 + c4]);
        }
      }
      #pragma unroll
      for (int im = 0; im < 2; ++im)
        #pragma unroll
        for (int in = 0; in < 2; ++in) {
          const int sloc = wn * 32 + in * 16 + fr;
          #pragma unroll
          for (int r = 0; r < 4; ++r) {
            const int qloc = wm * 32 + im * 16 + kg * 4 + r;
            __builtin_nontemporal_store(xv[im][in][r],
                                        &attb[(size_t)(q0 + qloc) * S + prev_s0 + sloc]);
          }
        }
    }
    __syncthreads();   // joint drain: K(st) [prefetched] + V loads + stores

    // ---- scores: identical accumulation order to stats_mfma ----
    f32x4 sacc[2][2] = {};
    __builtin_amdgcn_s_setprio(1);
    #pragma unroll
    for (int ks = 0; ks < 4; ++ks) {
      bf16x8 bh[2], bl[2];
      #pragma unroll
      for (int in = 0; in < 2; ++in) {
        const int row = wn * 32 + in * 16 + fr;
        const int off = row * 128 + ((ks * 4 + kg) ^ (row & 7)) * 8;
        bh[in] = *(const bf16x8*)&Ksh[off];
        bl[in] = *(const bf16x8*)&Ksl[off];
      }
      #pragma unroll
      for (int im = 0; im < 2; ++im)
        #pragma unroll
        for (int in = 0; in < 2; ++in) {
          sacc[im][in] = __builtin_amdgcn_mfma_f32_16x16x32_bf16(qfh[im][ks], bh[in], sacc[im][in], 0, 0, 0);
          sacc[im][in] = __builtin_amdgcn_mfma_f32_16x16x32_bf16(qfh[im][ks], bl[in], sacc[im][in], 0, 0, 0);
          sacc[im][in] = __builtin_amdgcn_mfma_f32_16x16x32_bf16(qfl[im][ks], bh[in], sacc[im][in], 0, 0, 0);
        }
    }
    __builtin_amdgcn_s_setprio(0);

    // ---- normalize in-register; P (plain bf16) -> LDS; keep xv in regs ----
    const bool diag = (st == qt);
    #pragma unroll
    for (int in = 0; in < 2; ++in) {
      const int sloc = wn * 32 + in * 16 + fr;
      const int scol = s0 + sloc;
      const float m   = cm[(size_t)b * S + scol];
      const float inv = cinv[(size_t)b * S + scol];
      #pragma unroll
      for (int im = 0; im < 2; ++im) {
        #pragma unroll
        for (int r = 0; r < 4; ++r) {
          const int qloc = wm * 32 + im * 16 + kg * 4 + r;
          const bool live = !diag || (q0 + qloc >= scol);
          const float x = live ? __expf(sacc[im][in][r] * SCALE - m) * inv : 0.f;
          xv[im][in][r] = x;
          const int idx = qloc * 64 + (((sloc >> 3) ^ (qloc & 7)) * 8 + (sloc & 7));
          Psh[idx] = f2bf(x);
        }
      }
    }
    __syncthreads();   // P visible; Ksh now dead

    // ---- prefetch next K tile into Ksh (hides under PV) ----
    if (st + NSP_PV <= qt) stage_K((st + NSP_PV) * 64);

    // ---- PV: wave w computes q rows [w*16, w*16+16), all 128 d cols ----
    __builtin_amdgcn_s_setprio(1);
    #pragma unroll
    for (int ks2 = 0; ks2 < 2; ++ks2) {
      const int arow = w * 16 + fr;
      const int aoff = arow * 64 + ((ks2 * 4 + kg) ^ (arow & 7)) * 8;
      const bf16x8 a = *(const bf16x8*)&Psh[aoff];
      #pragma unroll
      for (int in = 0; in < 8; ++in) {
        const int brow = in * 16 + fr;
        const int boff = brow * 64 + ((ks2 * 4 + kg) ^ (brow & 7)) * 8;
        const bf16x8 b_h = *(const bf16x8*)&Vsh[boff];
        const bf16x8 b_l = *(const bf16x8*)&Vsl[boff];
        acc[in] = __builtin_amdgcn_mfma_f32_16x16x32_bf16(a, b_h, acc[in], 0, 0, 0);
        acc[in] = __builtin_amdgcn_mfma_f32_16x16x32_bf16(a, b_l, acc[in], 0, 0, 0);
      }
    }
    __builtin_amdgcn_s_setprio(0);
    __syncthreads();   // Vsh/Psh reads done before next-iter V staging

    prev_s0 = s0;
    prev_mirror = (st < qt) ? 1 : 0;
  }

  // ---- final tile's deferred stores ----
  if (prev_s0 >= 0) {
    if (prev_mirror) {
      const f32x4 z = {0.f, 0.f, 0.f, 0.f};
      #pragma unroll
      for (int i = 0; i < 4; ++i) {
        const int flat = t + i * 256;
        const int row = flat >> 4, c4 = (flat & 15) * 4;
        __builtin_nontemporal_store(z, (f32x4*)&attb[(size_t)(prev_s0 + row) * S + q0 + c4]);
      }
    }
    #pragma unroll
    for (int im = 0; im < 2; ++im)
      #pragma unroll
      for (int in = 0; in < 2; ++in) {
        const int sloc = wn * 32 + in * 16 + fr;
        #pragma unroll
        for (int r = 0; r < 4; ++r) {
          const int qloc = wm * 32 + im * 16 + kg * 4 + r;
          __builtin_nontemporal_store(xv[im][in][r],
                                      &attb[(size_t)(q0 + qloc) * S + prev_s0 + sloc]);
        }
      }
  }

  // ---- single atomic epilogue per block ----
  #pragma unroll
  for (int in = 0; in < 8; ++in) {
    #pragma unroll
    for (int r = 0; r < 4; ++r) {
      const int q = q0 + w * 16 + kg * 4 + r;
      const int d = in * 16 + fr;
      atomicAdd(&out[((size_t)b * S + q) * DK + d], acc[in][r]);
    }
  }
}

// ---------------------------------------------------------------------------
extern "C" void kernel_launch(void* const* d_in, const int* in_sizes, int n_in,
                              void* d_out, int out_size, void* d_ws, size_t ws_size,
                              hipStream_t stream)
{
  const float* vin = (const float*)d_in[0];
  const float* wq  = (const float*)d_in[1];
  const float* wk  = (const float*)d_in[2];
  const float* wv  = (const float*)d_in[3];

  float* out = (float*)d_out;
  float* att = out + (size_t)B * S * DK;     // attention output region (64 MB)

  // bf16 W copies live INSIDE the att region (dead before att writes)
  unsigned short* Wth = (unsigned short*)att;
  unsigned short* Wtl = Wth + (size_t)384 * DM;

  constexpr size_t NE = (size_t)BS * DK;     // 1048576
  unsigned short* qh  = (unsigned short*)d_ws;
  unsigned short* ql  = qh  + NE;
  unsigned short* kh  = ql  + NE;
  unsigned short* kl  = kh  + NE;
  unsigned short* vTh = kl  + NE;
  unsigned short* vTl = vTh + NE;
  float* vtmp = (float*)(vTl + NE);          // 4 MB
  float* pm   = vtmp;                        // aliases vtmp (v dead by then)
  float* ps   = pm + 32ull * B * S;          // 1 MB each
  float* cm   = ps + 32ull * B * S;
  float* cinv = cm + (size_t)B * S;

  cvtw_kernel      <<<dim3(384),             256, 0, stream>>>(wq, wk, wv, Wth, Wtl);
  proj_mfma        <<<dim3(BS / 64, 6),      256, 0, stream>>>(vin, Wth, Wtl,
                                                               qh, ql, kh, kl, vtmp);
  cvtv_kernel      <<<dim3(S / 64, 2, B),    256, 0, stream>>>(vtmp, vTh, vTl);
  zero_out_kernel  <<<dim3(BS * DK / 1024),  256, 0, stream>>>(out);
  stats_mfma       <<<dim3(NSP, 32, B),      256, 0, stream>>>(qh, ql, kh, kl, pm, ps);
  colcombine_kernel<<<dim3(S / 256, B),      256, 0, stream>>>(pm, ps, cm, cinv);
  fused_pv         <<<dim3(NSP_PV, 32, B),   256, 0, stream>>>(qh, ql, kh, kl, vTh, vTl,
                                                               cm, cinv, att, out);
}

// Round 21
// 104.646 us; speedup vs baseline: 1.1358x; 1.0431x over previous
//
#include <hip/hip_runtime.h>
#include <math.h>

// Problem constants
constexpr int B  = 4;
constexpr int S  = 2048;
constexpr int DM = 1024;
constexpr int DK = 128;
constexpr int BS = B * S;
constexpr int NSP    = 8;   // st-split factor for stats
constexpr int NSP_PV = 4;   // st-split for fused_pv (one resident generation)

static constexpr float SCALE = 0.08838834764831845f; // 1/sqrt(128)

typedef __attribute__((ext_vector_type(8))) short bf16x8;
typedef __attribute__((ext_vector_type(4))) float f32x4;
typedef __attribute__((ext_vector_type(8))) unsigned short u16x8;

__device__ __forceinline__ unsigned short f2bf(float x) {
  unsigned u = __float_as_uint(x);
  unsigned r = (u + 0x7FFFu + ((u >> 16) & 1u)) >> 16;   // RNE
  return (unsigned short)r;
}
__device__ __forceinline__ unsigned short f2bf_tr(float x) {
  return (unsigned short)(__float_as_uint(x) >> 16);      // truncate
}
__device__ __forceinline__ float bf2f(unsigned short h) {
  return __uint_as_float(((unsigned)h) << 16);
}

__device__ __forceinline__ void gload16(const void* g, void* l) {
  __builtin_amdgcn_global_load_lds(
      (const __attribute__((address_space(1))) void*)g,
      (__attribute__((address_space(3))) void*)l, 16, 0, 0);
}

// ---------------------------------------------------------------------------
// Prep: w_q/w_k/w_v [1024][128] fp32 -> Wt hi/lo bf16 [384][1024] (B^T)
// ---------------------------------------------------------------------------
__global__ void cvtw_kernel(const float* __restrict__ wq, const float* __restrict__ wk,
                            const float* __restrict__ wv,
                            unsigned short* __restrict__ Wth, unsigned short* __restrict__ Wtl)
{
  const int n = blockIdx.x;            // 0..383
  const int p = n >> 7, c = n & 127;
  const float* w = (p == 0) ? wq : (p == 1) ? wk : wv;
  for (int k = threadIdx.x; k < DM; k += 256) {
    const float x = w[(size_t)k * DK + c];
    const unsigned short h = f2bf(x);
    Wth[(size_t)n * DM + k] = h;
    Wtl[(size_t)n * DM + k] = f2bf(x - bf2f(h));
  }
}

// ---------------------------------------------------------------------------
// Kernel A: projections via split-bf16 MFMA. A staged directly from vin
// (fp32): load float4, truncation hi/lo split in-register, swizzled ds_write.
// W staged via gload_lds from the cvtw output.
// ---------------------------------------------------------------------------
__global__ __launch_bounds__(256) void proj_mfma(
    const float* __restrict__ vin,
    const unsigned short* __restrict__ Wh, const unsigned short* __restrict__ Wl,
    unsigned short* __restrict__ qh, unsigned short* __restrict__ ql,
    unsigned short* __restrict__ kh, unsigned short* __restrict__ kl,
    float* __restrict__ vtmp)
{
  __shared__ unsigned short Ash[2][64 * 64];
  __shared__ unsigned short Wsh[2][64 * 64];

  const int r0 = blockIdx.x * 64;      // M tile
  const int n0 = blockIdx.y * 64;      // N tile (384/64 = 6)
  const int t  = threadIdx.x;
  const int l  = t & 63, w = t >> 6;
  const int wm = w >> 1, wn = w & 1;   // 2x2 wave grid
  const int fr = l & 15, kg = l >> 4;  // fragment row / k-group

  f32x4 acc[2][2] = {};

  for (int k0 = 0; k0 < DM; k0 += 64) {
    // ---- stage W 64x64 hi/lo via gload_lds (pre-swizzled source) ----
    #pragma unroll
    for (int i = 0; i < 2; ++i) {
      const int flat = t + i * 256;          // 512 16B segments per buffer
      const int row = flat >> 3, sg = flat & 7;
      const int sgs = sg ^ (row & 7);
      const size_t gw = (size_t)(n0 + row) * DM + k0 + sgs * 8;
      gload16(Wh + gw, &Wsh[0][flat * 8]);
      gload16(Wl + gw, &Wsh[1][flat * 8]);
    }
    // ---- stage A 64x64 from vin fp32: convert + swizzled ds_write ----
    #pragma unroll
    for (int i = 0; i < 4; ++i) {
      const int flat = t + i * 256;          // 0..1023 float4 slots
      const int row = flat >> 4;
      const int c4  = (flat & 15) * 4;
      const float4 a = *(const float4*)&vin[(size_t)(r0 + row) * DM + k0 + c4];
      ushort4 h, lo4;
      h.x = f2bf_tr(a.x); lo4.x = f2bf_tr(a.x - bf2f(h.x));
      h.y = f2bf_tr(a.y); lo4.y = f2bf_tr(a.y - bf2f(h.y));
      h.z = f2bf_tr(a.z); lo4.z = f2bf_tr(a.z - bf2f(h.z));
      h.w = f2bf_tr(a.w); lo4.w = f2bf_tr(a.w - bf2f(h.w));
      const int off = row * 64 + (((c4 >> 3) ^ (row & 7)) * 8) + (c4 & 7);
      *(ushort4*)&Ash[0][off] = h;
      *(ushort4*)&Ash[1][off] = lo4;
    }
    __syncthreads();

    __builtin_amdgcn_s_setprio(1);
    #pragma unroll
    for (int kk = 0; kk < 2; ++kk) {
      bf16x8 ah[2], al[2], bh[2], bl[2];
      #pragma unroll
      for (int im = 0; im < 2; ++im) {
        const int row = wm * 32 + im * 16 + fr;
        const int off = row * 64 + ((kk * 4 + kg) ^ (row & 7)) * 8;
        ah[im] = *(const bf16x8*)&Ash[0][off];
        al[im] = *(const bf16x8*)&Ash[1][off];
      }
      #pragma unroll
      for (int in = 0; in < 2; ++in) {
        const int row = wn * 32 + in * 16 + fr;
        const int off = row * 64 + ((kk * 4 + kg) ^ (row & 7)) * 8;
        bh[in] = *(const bf16x8*)&Wsh[0][off];
        bl[in] = *(const bf16x8*)&Wsh[1][off];
      }
      #pragma unroll
      for (int im = 0; im < 2; ++im)
        #pragma unroll
        for (int in = 0; in < 2; ++in) {
          acc[im][in] = __builtin_amdgcn_mfma_f32_16x16x32_bf16(ah[im], bh[in], acc[im][in], 0, 0, 0);
          acc[im][in] = __builtin_amdgcn_mfma_f32_16x16x32_bf16(ah[im], bl[in], acc[im][in], 0, 0, 0);
          acc[im][in] = __builtin_amdgcn_mfma_f32_16x16x32_bf16(al[im], bh[in], acc[im][in], 0, 0, 0);
        }
    }
    __builtin_amdgcn_s_setprio(0);
    __syncthreads();
  }

  // Epilogue: C/D layout col = lane&15, row = (lane>>4)*4 + reg
  const int crow = kg * 4;
  #pragma unroll
  for (int im = 0; im < 2; ++im)
    #pragma unroll
    for (int in = 0; in < 2; ++in) {
      const int n = n0 + wn * 32 + in * 16 + fr;
      const int p = n >> 7, c = n & 127;           // p uniform per block
      #pragma unroll
      for (int r = 0; r < 4; ++r) {
        const int m = r0 + wm * 32 + im * 16 + crow + r;
        const float val = acc[im][in][r];
        if (p == 2) {
          vtmp[(size_t)m * DK + c] = val;
        } else {
          const unsigned short h = f2bf(val);
          const unsigned short lo2 = f2bf(val - bf2f(h));
          unsigned short* hd = p ? kh : qh;
          unsigned short* ld = p ? kl : ql;
          hd[(size_t)m * DK + c] = h;
          ld[(size_t)m * DK + c] = lo2;
        }
      }
    }
}

// ---------------------------------------------------------------------------
// Prep 3: transpose v fp32 [B][S][128] -> vT bf16 (RNE) [B][128][S]
// (single buffer — PV uses plain-bf16 V; P's bf16 error dominates anyway)
// ---------------------------------------------------------------------------
__global__ __launch_bounds__(256) void cvtv_kernel(
    const float* __restrict__ v, unsigned short* __restrict__ vTh)
{
  const int s0 = blockIdx.x * 64, d0 = blockIdx.y * 64, b = blockIdx.z;
  __shared__ float Ts[64][65];
  const int t = threadIdx.x;
  const int r = t >> 4, c4 = (t & 15) * 4;
  #pragma unroll
  for (int rr = 0; rr < 4; ++rr) {
    const int sl = r + 16 * rr;
    *(float4*)&Ts[sl][c4] =
        *(const float4*)&v[((size_t)b * S + s0 + sl) * DK + d0 + c4];
  }
  __syncthreads();
  const int dl = t >> 2, sq = (t & 3) * 16;
  unsigned short hbuf[16];
  #pragma unroll
  for (int j = 0; j < 16; ++j)
    hbuf[j] = f2bf(Ts[sq + j][dl]);
  const size_t o = (size_t)b * DK * S + (size_t)(d0 + dl) * S + s0 + sq;
  #pragma unroll
  for (int half = 0; half < 2; ++half)
    *(u16x8*)&vTh[o + half * 8] = *(u16x8*)&hbuf[half * 8];
}

// ---------------------------------------------------------------------------
// Kernel B: column-softmax STATS ONLY. grid (NSP, 32, B); block (sp, qt)
// loops st = sp, sp+NSP, ... <= qt. Q staged once; K(st+NSP) prefetched
// after tile st's score MFMAs. 2 barriers/tile.
// ---------------------------------------------------------------------------
__global__ __launch_bounds__(256) void stats_mfma(
    const unsigned short* __restrict__ qh, const unsigned short* __restrict__ ql,
    const unsigned short* __restrict__ kh, const unsigned short* __restrict__ kl,
    float* __restrict__ pm, float* __restrict__ ps)
{
  const int sp = blockIdx.x, qt = blockIdx.y, b = blockIdx.z;
  if (sp > qt) return;
  const int q0 = qt * 64;

  __shared__ unsigned short Bsh[64 * 128], Bsl[64 * 128];   // Q stage / K
  __shared__ float SmL[64 * 2], SeL[64 * 2];

  const int t = threadIdx.x;
  const int l = t & 63, w = t >> 6;
  const int wm = w >> 1, wn = w & 1;
  const int fr = l & 15, kg = l >> 4;

  auto stage_K = [&](int s0k) {
    #pragma unroll
    for (int i = 0; i < 4; ++i) {
      const int flat = t + i * 256;
      const int row = flat >> 4, sg = flat & 15;
      const int sgs = sg ^ (row & 7);
      const size_t gk = (size_t)(b * S + s0k + row) * DK + sgs * 8;
      gload16(kh + gk, &Bsh[flat * 8]);
      gload16(kl + gk, &Bsl[flat * 8]);
    }
  };

  // ---- stage Q once, pull fragments to registers ----
  #pragma unroll
  for (int i = 0; i < 4; ++i) {
    const int flat = t + i * 256;
    const int row = flat >> 4, sg = flat & 15;
    const int sgs = sg ^ (row & 7);
    const size_t gq = (size_t)(b * S + q0 + row) * DK + sgs * 8;
    gload16(qh + gq, &Bsh[flat * 8]);
    gload16(ql + gq, &Bsl[flat * 8]);
  }
  __syncthreads();
  bf16x8 qfh[2][4], qfl[2][4];
  #pragma unroll
  for (int im = 0; im < 2; ++im)
    #pragma unroll
    for (int ks = 0; ks < 4; ++ks) {
      const int row = wm * 32 + im * 16 + fr;
      const int off = row * 128 + ((ks * 4 + kg) ^ (row & 7)) * 8;
      qfh[im][ks] = *(const bf16x8*)&Bsh[off];
      qfl[im][ks] = *(const bf16x8*)&Bsl[off];
    }
  __syncthreads();   // Q reads done before K overwrites

  stage_K(sp * 64);  // prologue: first K tile

  for (int st = sp; st <= qt; st += NSP) {
    const int s0 = st * 64;
    __syncthreads();   // drains K(st); orders prev SmL/SeL reuse

    // ---- scores (order must match fused_pv exactly) ----
    f32x4 sacc[2][2] = {};
    __builtin_amdgcn_s_setprio(1);
    #pragma unroll
    for (int ks = 0; ks < 4; ++ks) {
      bf16x8 bh[2], bl[2];
      #pragma unroll
      for (int in = 0; in < 2; ++in) {
        const int row = wn * 32 + in * 16 + fr;
        const int off = row * 128 + ((ks * 4 + kg) ^ (row & 7)) * 8;
        bh[in] = *(const bf16x8*)&Bsh[off];
        bl[in] = *(const bf16x8*)&Bsl[off];
      }
      #pragma unroll
      for (int im = 0; im < 2; ++im)
        #pragma unroll
        for (int in = 0; in < 2; ++in) {
          sacc[im][in] = __builtin_amdgcn_mfma_f32_16x16x32_bf16(qfh[im][ks], bh[in], sacc[im][in], 0, 0, 0);
          sacc[im][in] = __builtin_amdgcn_mfma_f32_16x16x32_bf16(qfh[im][ks], bl[in], sacc[im][in], 0, 0, 0);
          sacc[im][in] = __builtin_amdgcn_mfma_f32_16x16x32_bf16(qfl[im][ks], bh[in], sacc[im][in], 0, 0, 0);
        }
    }
    __builtin_amdgcn_s_setprio(0);

    // ---- prefetch next K tile (Bsh dead now; hides under stats VALU) ----
    if (st + NSP <= qt) stage_K((st + NSP) * 64);

    // ---- column stats (softmax over q within this 64-row chunk) ----
    const bool diag = (st == qt);
    float Sm_[2], Se_[2];
    #pragma unroll
    for (int in = 0; in < 2; ++in) {
      const int scol = s0 + wn * 32 + in * 16 + fr;
      float m8 = -INFINITY;
      #pragma unroll
      for (int im = 0; im < 2; ++im)
        #pragma unroll
        for (int r = 0; r < 4; ++r) {
          const int q = q0 + wm * 32 + im * 16 + kg * 4 + r;
          if (!diag || q >= scol) m8 = fmaxf(m8, sacc[im][in][r] * SCALE);
        }
      float e8 = 0.f;
      if (m8 > -INFINITY) {
        #pragma unroll
        for (int im = 0; im < 2; ++im)
          #pragma unroll
          for (int r = 0; r < 4; ++r) {
            const int q = q0 + wm * 32 + im * 16 + kg * 4 + r;
            if (!diag || q >= scol) e8 += __expf(sacc[im][in][r] * SCALE - m8);
          }
      }
      #pragma unroll
      for (int off = 16; off <= 32; off <<= 1) {
        const float om = __shfl_xor(m8, off);
        const float oe = __shfl_xor(e8, off);
        const float nm = fmaxf(m8, om);
        float ne = 0.f;
        if (m8 > -INFINITY) ne += e8 * __expf(m8 - nm);
        if (om > -INFINITY) ne += oe * __expf(om - nm);
        m8 = nm; e8 = ne;
      }
      Sm_[in] = m8; Se_[in] = e8;
    }
    if (l < 16) {
      #pragma unroll
      for (int in = 0; in < 2; ++in) {
        const int col = wn * 32 + in * 16 + l;
        SmL[col * 2 + wm] = Sm_[in];
        SeL[col * 2 + wm] = Se_[in];
      }
    }
    __syncthreads();
    if (t < 64) {
      const float m0 = SmL[t * 2 + 0], m1 = SmL[t * 2 + 1];
      const float nm = fmaxf(m0, m1);
      float ne = 0.f;
      if (m0 > -INFINITY) ne += SeL[t * 2 + 0] * __expf(m0 - nm);
      if (m1 > -INFINITY) ne += SeL[t * 2 + 1] * __expf(m1 - nm);
      const size_t o = ((size_t)(b * 32 + qt)) * S + s0 + t;
      pm[o] = nm;
      ps[o] = ne;
    }
    // loop-top barrier orders SmL reuse + drains prefetched K
  }
}

// ---------------------------------------------------------------------------
// Kernel C: combine 32 row-chunk partials -> per-column max m and 1/sum.
// ---------------------------------------------------------------------------
__global__ void colcombine_kernel(const float* __restrict__ pm, const float* __restrict__ ps,
                                  float* __restrict__ cm, float* __restrict__ cinv)
{
  const int s = blockIdx.x * 256 + threadIdx.x;
  const int b = blockIdx.y;
  const int ch0 = s >> 6;
  float m = -INFINITY;
  for (int ch = ch0; ch < 32; ++ch)
    m = fmaxf(m, pm[((size_t)(b * 32 + ch)) * S + s]);
  float sum = 0.f;
  for (int ch = ch0; ch < 32; ++ch) {
    const size_t i = ((size_t)(b * 32 + ch)) * S + s;
    sum += ps[i] * __expf(pm[i] - m);
  }
  cm[(size_t)b * S + s]   = m;
  cinv[(size_t)b * S + s] = 1.f / sum;   // sum >= 1 (diagonal element)
}

// ---------------------------------------------------------------------------
// zero out (out is atomically accumulated)
// ---------------------------------------------------------------------------
__global__ void zero_out_kernel(float* __restrict__ out)
{
  const size_t idx = (size_t)blockIdx.x * 256 + threadIdx.x;
  ((float4*)out)[idx] = float4{0.f, 0.f, 0.f, 0.f};
}

// ---------------------------------------------------------------------------
// Kernel D: fused second pass. grid (NSP_PV, 32, B) = 488 active blocks —
// one co-resident generation. V now PLAIN bf16 (16 KB/tile, 8 PV MFMA/wave
// instead of 16 — round-21 lever; P's bf16 error dominates the product).
// Pipeline: V(st) issued at top with prev tile's deferred att/mirror stores
// in its shadow; K(st+NSP_PV) issued after the P-visible barrier. One
// atomic epilogue per block. Scores recomputed bitwise-identical to
// stats_mfma. LDS 56 KB.
// ---------------------------------------------------------------------------
__global__ __launch_bounds__(256) void fused_pv(
    const unsigned short* __restrict__ qh, const unsigned short* __restrict__ ql,
    const unsigned short* __restrict__ kh, const unsigned short* __restrict__ kl,
    const unsigned short* __restrict__ vTh,
    const float* __restrict__ cm, const float* __restrict__ cinv,
    float* __restrict__ att, float* __restrict__ out)
{
  const int sp = blockIdx.x, qt = blockIdx.y, b = blockIdx.z;
  if (sp > qt) return;
  const int q0 = qt * 64;
  float* attb = att + (size_t)b * S * S;
  const unsigned short* vth = vTh + (size_t)b * DK * S;

  __shared__ unsigned short Ksh[64 * 128], Ksl[64 * 128];   // Q stage / K (32 KB)
  __shared__ unsigned short Vsh[128 * 64];                  // vT tile (16 KB)
  __shared__ unsigned short Psh[64 * 64];                   // P tile (8 KB)

  const int t = threadIdx.x;
  const int l = t & 63, w = t >> 6;
  const int wm = w >> 1, wn = w & 1;          // 2x2 wave grid (scores)
  const int fr = l & 15, kg = l >> 4;

  auto stage_K = [&](int s0k) {
    #pragma unroll
    for (int i = 0; i < 4; ++i) {
      const int flat = t + i * 256;
      const int row = flat >> 4, sg = flat & 15;
      const int sgs = sg ^ (row & 7);
      const size_t gk = (size_t)(b * S + s0k + row) * DK + sgs * 8;
      gload16(kh + gk, &Ksh[flat * 8]);
      gload16(kl + gk, &Ksl[flat * 8]);
    }
  };

  // ---- stage Q tile once, pull fragments to registers ----
  #pragma unroll
  for (int i = 0; i < 4; ++i) {
    const int flat = t + i * 256;
    const int row = flat >> 4, sg = flat & 15;
    const int sgs = sg ^ (row & 7);
    const size_t gq = (size_t)(b * S + q0 + row) * DK + sgs * 8;
    gload16(qh + gq, &Ksh[flat * 8]);
    gload16(ql + gq, &Ksl[flat * 8]);
  }
  __syncthreads();
  bf16x8 qfh[2][4], qfl[2][4];
  #pragma unroll
  for (int im = 0; im < 2; ++im)
    #pragma unroll
    for (int ks = 0; ks < 4; ++ks) {
      const int row = wm * 32 + im * 16 + fr;
      const int off = row * 128 + ((ks * 4 + kg) ^ (row & 7)) * 8;
      qfh[im][ks] = *(const bf16x8*)&Ksh[off];
      qfl[im][ks] = *(const bf16x8*)&Ksl[off];
    }
  __syncthreads();   // all Q reads done before K overwrites

  stage_K(sp * 64);  // prologue: first K tile

  f32x4 acc[8] = {};     // PV accumulator, persists across st tiles
  float xv[2][2][4];     // previous tile's normalized att values
  int prev_s0 = -1;
  int prev_mirror = 0;

  for (int st = sp; st <= qt; st += NSP_PV) {
    const int s0 = st * 64;

    // ---- stage V tile (issue; plain bf16) ----
    #pragma unroll
    for (int i = 0; i < 4; ++i) {
      const int flat = t + i * 256;
      const int row = flat >> 3, sg = flat & 7;
      const int sgs = sg ^ (row & 7);
      const size_t gv = (size_t)row * S + s0 + sgs * 8;
      gload16(vth + gv, &Vsh[flat * 8]);
    }

    // ---- deferred att/mirror stores for the PREVIOUS tile (load shadow) ----
    if (prev_s0 >= 0) {
      if (prev_mirror) {
        const f32x4 z = {0.f, 0.f, 0.f, 0.f};
        #pragma unroll
        for (int i = 0; i < 4; ++i) {
          const int flat = t + i * 256;
          const int row = flat >> 4, c4 = (flat & 15) * 4;
          __builtin_nontemporal_store(z, (f32x4*)&attb[(size_t)(prev_s0 + row) * S + q0 + c4]);
        }
      }
      #pragma unroll
      for (int im = 0; im < 2; ++im)
        #pragma unroll
        for (int in = 0; in < 2; ++in) {
          const int sloc = wn * 32 + in * 16 + fr;
          #pragma unroll
          for (int r = 0; r < 4; ++r) {
            const int qloc = wm * 32 + im * 16 + kg * 4 + r;
            __builtin_nontemporal_store(xv[im][in][r],
                                        &attb[(size_t)(q0 + qloc) * S + prev_s0 + sloc]);
          }
        }
    }
    __syncthreads();   // joint drain: K(st) [prefetched] + V loads + stores

    // ---- scores: identical accumulation order to stats_mfma ----
    f32x4 sacc[2][2] = {};
    __builtin_amdgcn_s_setprio(1);
    #pragma unroll
    for (int ks = 0; ks < 4; ++ks) {
      bf16x8 bh[2], bl[2];
      #pragma unroll
      for (int in = 0; in < 2; ++in) {
        const int row = wn * 32 + in * 16 + fr;
        const int off = row * 128 + ((ks * 4 + kg) ^ (row & 7)) * 8;
        bh[in] = *(const bf16x8*)&Ksh[off];
        bl[in] = *(const bf16x8*)&Ksl[off];
      }
      #pragma unroll
      for (int im = 0; im < 2; ++im)
        #pragma unroll
        for (int in = 0; in < 2; ++in) {
          sacc[im][in] = __builtin_amdgcn_mfma_f32_16x16x32_bf16(qfh[im][ks], bh[in], sacc[im][in], 0, 0, 0);
          sacc[im][in] = __builtin_amdgcn_mfma_f32_16x16x32_bf16(qfh[im][ks], bl[in], sacc[im][in], 0, 0, 0);
          sacc[im][in] = __builtin_amdgcn_mfma_f32_16x16x32_bf16(qfl[im][ks], bh[in], sacc[im][in], 0, 0, 0);
        }
    }
    __builtin_amdgcn_s_setprio(0);

    // ---- normalize in-register; P (plain bf16) -> LDS; keep xv in regs ----
    const bool diag = (st == qt);
    #pragma unroll
    for (int in = 0; in < 2; ++in) {
      const int sloc = wn * 32 + in * 16 + fr;
      const int scol = s0 + sloc;
      const float m   = cm[(size_t)b * S + scol];
      const float inv = cinv[(size_t)b * S + scol];
      #pragma unroll
      for (int im = 0; im < 2; ++im) {
        #pragma unroll
        for (int r = 0; r < 4; ++r) {
          const int qloc = wm * 32 + im * 16 + kg * 4 + r;
          const bool live = !diag || (q0 + qloc >= scol);
          const float x = live ? __expf(sacc[im][in][r] * SCALE - m) * inv : 0.f;
          xv[im][in][r] = x;
          const int idx = qloc * 64 + (((sloc >> 3) ^ (qloc & 7)) * 8 + (sloc & 7));
          Psh[idx] = f2bf(x);
        }
      }
    }
    __syncthreads();   // P visible; Ksh now dead

    // ---- prefetch next K tile into Ksh (hides under PV) ----
    if (st + NSP_PV <= qt) stage_K((st + NSP_PV) * 64);

    // ---- PV: wave w computes q rows [w*16, w*16+16), all 128 d cols ----
    __builtin_amdgcn_s_setprio(1);
    #pragma unroll
    for (int ks2 = 0; ks2 < 2; ++ks2) {
      const int arow = w * 16 + fr;
      const int aoff = arow * 64 + ((ks2 * 4 + kg) ^ (arow & 7)) * 8;
      const bf16x8 a = *(const bf16x8*)&Psh[aoff];
      #pragma unroll
      for (int in = 0; in < 8; ++in) {
        const int brow = in * 16 + fr;
        const int boff = brow * 64 + ((ks2 * 4 + kg) ^ (brow & 7)) * 8;
        const bf16x8 b_h = *(const bf16x8*)&Vsh[boff];
        acc[in] = __builtin_amdgcn_mfma_f32_16x16x32_bf16(a, b_h, acc[in], 0, 0, 0);
      }
    }
    __builtin_amdgcn_s_setprio(0);
    __syncthreads();   // Vsh/Psh reads done before next-iter V staging

    prev_s0 = s0;
    prev_mirror = (st < qt) ? 1 : 0;
  }

  // ---- final tile's deferred stores ----
  if (prev_s0 >= 0) {
    if (prev_mirror) {
      const f32x4 z = {0.f, 0.f, 0.f, 0.f};
      #pragma unroll
      for (int i = 0; i < 4; ++i) {
        const int flat = t + i * 256;
        const int row = flat >> 4, c4 = (flat & 15) * 4;
        __builtin_nontemporal_store(z, (f32x4*)&attb[(size_t)(prev_s0 + row) * S + q0 + c4]);
      }
    }
    #pragma unroll
    for (int im = 0; im < 2; ++im)
      #pragma unroll
      for (int in = 0; in < 2; ++in) {
        const int sloc = wn * 32 + in * 16 + fr;
        #pragma unroll
        for (int r = 0; r < 4; ++r) {
          const int qloc = wm * 32 + im * 16 + kg * 4 + r;
          __builtin_nontemporal_store(xv[im][in][r],
                                      &attb[(size_t)(q0 + qloc) * S + prev_s0 + sloc]);
        }
      }
  }

  // ---- single atomic epilogue per block ----
  #pragma unroll
  for (int in = 0; in < 8; ++in) {
    #pragma unroll
    for (int r = 0; r < 4; ++r) {
      const int q = q0 + w * 16 + kg * 4 + r;
      const int d = in * 16 + fr;
      atomicAdd(&out[((size_t)b * S + q) * DK + d], acc[in][r]);
    }
  }
}

// ---------------------------------------------------------------------------
extern "C" void kernel_launch(void* const* d_in, const int* in_sizes, int n_in,
                              void* d_out, int out_size, void* d_ws, size_t ws_size,
                              hipStream_t stream)
{
  const float* vin = (const float*)d_in[0];
  const float* wq  = (const float*)d_in[1];
  const float* wk  = (const float*)d_in[2];
  const float* wv  = (const float*)d_in[3];

  float* out = (float*)d_out;
  float* att = out + (size_t)B * S * DK;     // attention output region (64 MB)

  // bf16 W copies live INSIDE the att region (dead before att writes)
  unsigned short* Wth = (unsigned short*)att;
  unsigned short* Wtl = Wth + (size_t)384 * DM;

  constexpr size_t NE = (size_t)BS * DK;     // 1048576
  unsigned short* qh  = (unsigned short*)d_ws;
  unsigned short* ql  = qh  + NE;
  unsigned short* kh  = ql  + NE;
  unsigned short* kl  = kh  + NE;
  unsigned short* vTh = kl  + NE;
  float* vtmp = (float*)(vTh + NE);          // 4 MB
  float* pm   = vtmp;                        // aliases vtmp (v dead by then)
  float* ps   = pm + 32ull * B * S;          // 1 MB each
  float* cm   = ps + 32ull * B * S;
  float* cinv = cm + (size_t)B * S;

  cvtw_kernel      <<<dim3(384),             256, 0, stream>>>(wq, wk, wv, Wth, Wtl);
  proj_mfma        <<<dim3(BS / 64, 6),      256, 0, stream>>>(vin, Wth, Wtl,
                                                               qh, ql, kh, kl, vtmp);
  cvtv_kernel      <<<dim3(S / 64, 2, B),    256, 0, stream>>>(vtmp, vTh);
  zero_out_kernel  <<<dim3(BS * DK / 1024),  256, 0, stream>>>(out);
  stats_mfma       <<<dim3(NSP, 32, B),      256, 0, stream>>>(qh, ql, kh, kl, pm, ps);
  colcombine_kernel<<<dim3(S / 256, B),      256, 0, stream>>>(pm, ps, cm, cinv);
  fused_pv         <<<dim3(NSP_PV, 32, B),   256, 0, stream>>>(qh, ql, kh, kl, vTh,
                                                               cm, cinv, att, out);
}